// Round 12
// baseline (1374.119 us; speedup 1.0000x reference)
//
#include <hip/hip_runtime.h>
#include <stdint.h>

#define B_GRAPHS 4096
#define NPG 40
#define NTOT (B_GRAPHS * NPG)      // 163840
#define EPG 160
#define ETOT (B_GRAPHS * EPG)      // 655360
#define ESL 200                    // 160 edges + 40 self-loop slots
#define F_IN 78
#define KP0 96                     // F_IN padded to multiple of 32
#define HID 128
#define D0 512
#define CMB 520
#define BN_EPS 1e-5f
#define KPM 544                    // CMB padded to multiple of 32 (17*32)
#define A0ST 552                   // LDS stride for act0 (bank-spread)
#define H1ST 264                   // LDS stride for h1
#define H2ST 132                   // LDS stride for h2 (fp32)

typedef short bf16x8 __attribute__((ext_vector_type(8)));
typedef float floatx4 __attribute__((ext_vector_type(4)));

__device__ inline float b2f(unsigned short u) {
    union { float f; uint32_t i; } v; v.i = ((uint32_t)u) << 16; return v.f;
}
__device__ inline unsigned short f2b(float f) {
    union { float f; uint32_t i; } v; v.f = f;
    uint32_t x = v.i;
    return (unsigned short)((x + 0x7fffu + ((x >> 16) & 1u)) >> 16);
}
__device__ inline float lo16(uint32_t u) {
    union { float f; uint32_t i; } v; v.i = u << 16; return v.f;
}
__device__ inline float hi16(uint32_t u) {
    union { float f; uint32_t i; } v; v.i = u & 0xffff0000u; return v.f;
}
// transposed-h LDS layout: row = channel (stride 40 u16 = 80 B), the five
// 16B chunks of each row are rotated by (ch % 5) to spread banks across rows.
__device__ inline int htoff(int ch, int s) {
    int chunk = s >> 3, within = s & 7;
    return ch * 40 + (((chunk + ch) % 5) << 3) + within;
}
// async global->LDS 16B (wave-uniform LDS base; per-lane global source)
__device__ inline void gl2lds16(const unsigned short* g, unsigned short* l) {
    __builtin_amdgcn_global_load_lds(
        (const __attribute__((address_space(1))) unsigned int*)g,
        (__attribute__((address_space(3))) unsigned int*)l, 16, 0, 0);
}

__global__ __launch_bounds__(256)
void write_code_kernel(float* __restrict__ out, int n, float S)
{
    int i = blockIdx.x * 256 + threadIdx.x;
    if (i < n) out[i] = (i == 0) ? S : 0.f;
}

// ---------------------------------------------------------------------------
// Weight convert: W [K,N] fp32 -> Wt [N,Kp] bf16 (transposed, zero-padded K)
// ---------------------------------------------------------------------------
__global__ __launch_bounds__(256)
void convw_kernel(const float* __restrict__ W, unsigned short* __restrict__ Wt,
                  int K, int N, int Kp)
{
    int t = blockIdx.x * 256 + threadIdx.x;
    if (t >= N * Kp) return;
    int n = t / Kp, k = t - n * Kp;
    Wt[t] = (k < K) ? f2b(W[(size_t)k * N + n]) : 0;
}

// Weight convert, hi/lo split: W [K,N] fp32 -> Whi/Wlo [N,Kp] bf16
__global__ __launch_bounds__(256)
void convw_hilo_kernel(const float* __restrict__ W,
                       unsigned short* __restrict__ Whi,
                       unsigned short* __restrict__ Wlo,
                       int K, int N, int Kp)
{
    int t = blockIdx.x * 256 + threadIdx.x;
    if (t >= N * Kp) return;
    int n = t / Kp, k = t - n * Kp;
    float x = (k < K) ? W[(size_t)k * N + n] : 0.f;
    unsigned short hb = f2b(x);
    Whi[t] = hb;
    Wlo[t] = f2b(x - b2f(hb));
}

// av convert: avs/avd [K] fp32 -> avpk [4][K] bf16 rows
// {avs_hi, avd_hi, avs_lo, avd_lo} for the MFMA logits path.
__global__ __launch_bounds__(256)
void convav_kernel(const float* __restrict__ avs, const float* __restrict__ avd,
                   unsigned short* __restrict__ out, int K)
{
    int t = blockIdx.x * 256 + threadIdx.x;
    if (t >= 4 * K) return;
    int row = t / K, k = t - row * K;
    float x = (row & 1) ? avd[k] : avs[k];
    unsigned short hb = f2b(x);
    out[t] = (row < 2) ? hb : f2b(x - b2f(hb));
}

// x convert: X [M,78] fp32 -> Xb [M,96] bf16 zero-padded; 8 outputs/thread
__global__ __launch_bounds__(256)
void convx_kernel(const float* __restrict__ X, unsigned short* __restrict__ Xb, int M)
{
    int t = blockIdx.x * 256 + threadIdx.x;
    if (t >= M * (KP0 / 8)) return;
    int r = t / (KP0 / 8), c8 = t - r * (KP0 / 8);
    unsigned int pk[4];
    #pragma unroll
    for (int j = 0; j < 4; j++) {
        int k0 = c8 * 8 + 2 * j, k1 = k0 + 1;
        float x0 = (k0 < F_IN) ? X[(size_t)r * F_IN + k0] : 0.f;
        float x1 = (k1 < F_IN) ? X[(size_t)r * F_IN + k1] : 0.f;
        pk[j] = (unsigned int)f2b(x0) | ((unsigned int)f2b(x1) << 16);
    }
    *(uint4*)&Xb[(size_t)r * KP0 + c8 * 8] = make_uint4(pk[0], pk[1], pk[2], pk[3]);
}

// ---------------------------------------------------------------------------
// MFMA GEMM: C[M,N] = A[M,K] @ Bt[N,K]^T, bf16 in/out, fp32 accum.
// 128x128 tile, BK=32, 4 waves (2x2), 4x4 16x16 frags/wave.
// global_load_lds w=16 staging + swizzled ds_read_b128; swapped-operand
// MFMA -> packed uint2 stores; bijective XCD block swizzle (T1/m204).
// VGPR=68 -> 7 waves/SIMD; do NOT add register-hungry epilogues (R10 cliff).
// ---------------------------------------------------------------------------
__global__ __launch_bounds__(256)
void gemm_mfma_kernel(const unsigned short* __restrict__ A,
                      const unsigned short* __restrict__ Bt,
                      unsigned short* __restrict__ C,
                      int M, int K, int N)
{
    __shared__ __align__(16) unsigned short As[128 * 32];   // 8 KB
    __shared__ __align__(16) unsigned short Bs[128 * 32];   // 8 KB
    const int tid  = threadIdx.x;
    const int lane = tid & 63, w = tid >> 6;
    const int quad = lane >> 4, l16 = lane & 15;
    const int wm = w >> 1, wn = w & 1;
    // bijective XCD swizzle
    const int nwg  = gridDim.x * gridDim.y;
    const int orig = blockIdx.y * gridDim.x + blockIdx.x;
    const int q = nwg >> 3, r = nwg & 7;
    const int xcd = orig & 7, off = orig >> 3;
    const int swz = (xcd < r ? xcd * (q + 1) : r * (q + 1) + (xcd - r) * q) + off;
    const int row0 = (swz / gridDim.x) * 128, col0 = (swz % gridDim.x) * 128;

    floatx4 acc[4][4];
    #pragma unroll
    for (int mi = 0; mi < 4; mi++)
        #pragma unroll
        for (int ni = 0; ni < 4; ni++)
            acc[mi][ni] = (floatx4){0.f, 0.f, 0.f, 0.f};

    int srow[2], scg[2];
    #pragma unroll
    for (int it = 0; it < 2; it++) {
        int L = it * 4096 + w * 1024 + lane * 16;
        int rr = L >> 6;
        int cp = (L >> 4) & 3;
        srow[it] = rr;
        scg[it]  = cp ^ ((rr >> 1) & 3);
    }

    for (int k0 = 0; k0 < K; k0 += 32) {
        #pragma unroll
        for (int it = 0; it < 2; it++) {
            int ra = row0 + srow[it]; if (ra >= M) ra = M - 1;
            gl2lds16(A + (size_t)ra * K + k0 + scg[it] * 8,
                     As + (it * 4096 + w * 1024) / 2);
            int rb = col0 + srow[it];
            gl2lds16(Bt + (size_t)rb * K + k0 + scg[it] * 8,
                     Bs + (it * 4096 + w * 1024) / 2);
        }
        __syncthreads();

        bf16x8 fA[4], fB[4];
        #pragma unroll
        for (int mi = 0; mi < 4; mi++) {
            int rr = wm * 64 + mi * 16 + l16;
            __builtin_memcpy(&fA[mi], &As[rr * 32 + ((quad ^ ((rr >> 1) & 3)) * 8)], 16);
        }
        #pragma unroll
        for (int ni = 0; ni < 4; ni++) {
            int rr = wn * 64 + ni * 16 + l16;
            __builtin_memcpy(&fB[ni], &Bs[rr * 32 + ((quad ^ ((rr >> 1) & 3)) * 8)], 16);
        }
        #pragma unroll
        for (int mi = 0; mi < 4; mi++)
            #pragma unroll
            for (int ni = 0; ni < 4; ni++)
                acc[mi][ni] = __builtin_amdgcn_mfma_f32_16x16x32_bf16(
                    fB[ni], fA[mi], acc[mi][ni], 0, 0, 0);
        __syncthreads();
    }

    #pragma unroll
    for (int mi = 0; mi < 4; mi++) {
        int row = row0 + wm * 64 + mi * 16 + l16;
        if (row < M) {
            #pragma unroll
            for (int ni = 0; ni < 4; ni++) {
                floatx4 a = acc[mi][ni];
                unsigned int p0 = (unsigned int)f2b(a[0]) | ((unsigned int)f2b(a[1]) << 16);
                unsigned int p1 = (unsigned int)f2b(a[2]) | ((unsigned int)f2b(a[3]) << 16);
                *(uint2*)(C + (size_t)row * N + col0 + wn * 64 + ni * 16 + quad * 4) =
                    make_uint2(p0, p1);
            }
        }
    }
}

// ---------------------------------------------------------------------------
// Fused GAT (4 heads x 128, concat 512) + bias + BN + ReLU. In-place on H.
// NEW: logits computed on the MATRIX pipe in phase 0 (overlapped with ht
// staging): es/ed = h @ {avs,avd} via 12 MFMAs/wave with a 4-row hi/lo bf16
// av table (P) and h rows loaded from global Hg (Q). Replaces the ~830-VALU-op
// logits loop (gat4 is VALU-bound, R8). Verified fragment contract:
// mfma(P,Q): lane(quad,l16) reg rr = sum_k P[quad*4+rr][k]*Q[l16][k].
// ---------------------------------------------------------------------------
__global__ __launch_bounds__(256)
void gat4_fused_kernel(unsigned short* __restrict__ H,     // [chunk*40, 512]
                       const int* __restrict__ edge,
                       const unsigned short* __restrict__ avpk, // [4][512] bf16
                       const float* __restrict__ bias,
                       const float* __restrict__ bng, const float* __restrict__ bnb,
                       const float* __restrict__ bnm, const float* __restrict__ bnv,
                       int g0)
{
    __shared__ __align__(16) unsigned short ht[D0 * NPG];   // 40960 B [512][40]
    __shared__ float es[4 * NPG], ed[4 * NPG];              // [head][node]
    __shared__ __align__(16) unsigned char cnt[NPG * 48];   // [dn][s]
    __shared__ short2 eloc[ESL];
    const int tid = threadIdx.x;
    const int lane = tid & 63, w = tid >> 6;                // wave = head
    const int quad = lane >> 4, l16 = lane & 15;
    const int gg = g0 + blockIdx.x;
    unsigned short* Hg = H + (size_t)blockIdx.x * NPG * D0;

    // ---- phase 0: init + edge load + transpose-stage ----
    for (int i = tid; i < NPG * 48 / 4; i += 256) ((unsigned int*)cnt)[i] = 0u;
    for (int i = tid; i < ESL; i += 256) {
        if (i < EPG) {
            int s  = edge[(size_t)gg * EPG + i] - gg * NPG;
            int dd = edge[(size_t)ETOT + (size_t)gg * EPG + i] - gg * NPG;
            eloc[i] = make_short2((short)s, (short)dd);
        } else {
            short v = (short)(i - EPG);
            eloc[i] = make_short2(v, v);
        }
    }
    for (int u = tid; u < 64 * (NPG / 4); u += 256) {       // 640 units
        int c8 = u & 63, gi = u >> 6;
        const unsigned short* src = Hg + (size_t)(4 * gi) * D0 + c8 * 8;
        uint4 v0 = *(const uint4*)(src);
        uint4 v1 = *(const uint4*)(src + D0);
        uint4 v2 = *(const uint4*)(src + 2 * D0);
        uint4 v3 = *(const uint4*)(src + 3 * D0);
        unsigned int a0[4] = {v0.x, v0.y, v0.z, v0.w};
        unsigned int a1[4] = {v1.x, v1.y, v1.z, v1.w};
        unsigned int a2[4] = {v2.x, v2.y, v2.z, v2.w};
        unsigned int a3[4] = {v3.x, v3.y, v3.z, v3.w};
        #pragma unroll
        for (int k = 0; k < 8; k++) {
            const int ws = k >> 1, sh = (k & 1) * 16;
            unsigned int w0 = ((a0[ws] >> sh) & 0xffffu) | (((a1[ws] >> sh) & 0xffffu) << 16);
            unsigned int w1 = ((a2[ws] >> sh) & 0xffffu) | (((a3[ws] >> sh) & 0xffffu) << 16);
            *(uint2*)&ht[htoff(c8 * 8 + k, 4 * gi)] = make_uint2(w0, w1);
        }
    }
    // ---- phase 0b: logits via MFMA (reads Hg; independent of ht stores) ----
    {
        bf16x8 fP[4];
        #pragma unroll
        for (int kk = 0; kk < 4; kk++)
            __builtin_memcpy(&fP[kk],
                avpk + (l16 & 3) * D0 + w * 128 + kk * 32 + quad * 8, 16);
        #pragma unroll
        for (int mt = 0; mt < 3; mt++) {
            int node = mt * 16 + l16; if (node >= NPG) node = NPG - 1;
            const unsigned short* hrow = Hg + (size_t)node * D0 + w * 128;
            floatx4 la = {0.f, 0.f, 0.f, 0.f};
            #pragma unroll
            for (int kk = 0; kk < 4; kk++) {
                bf16x8 fQ;
                __builtin_memcpy(&fQ, hrow + kk * 32 + quad * 8, 16);
                la = __builtin_amdgcn_mfma_f32_16x16x32_bf16(fP[kk], fQ, la, 0, 0, 0);
            }
            if (quad == 0) {
                int nd = mt * 16 + l16;
                if (nd < NPG) {
                    es[w * NPG + nd] = la[0] + la[2];   // avs_hi + avs_lo
                    ed[w * NPG + nd] = la[1] + la[3];   // avd_hi + avd_lo
                }
            }
        }
    }
    __syncthreads();

    // ---- phase 1: edge-count build ----
    for (int e = tid; e < ESL; e += 256) {
        short2 sd = eloc[e];
        atomicAdd((unsigned int*)cnt + ((sd.y * 48 + sd.x) >> 2),
                  1u << ((sd.x & 3) * 8));
    }
    __syncthreads();

    // ---- phase 2: in-register alpha (masked max + den via shfl) + MFMA ----
    {
        bf16x8 ahi[3][2], alo[3][2];
        float esv0[8], esv1[8];
        #pragma unroll
        for (int j = 0; j < 8; j++) {
            esv0[j] = es[w * NPG + quad * 8 + j];
            esv1[j] = (quad == 0) ? es[w * NPG + 32 + j] : 0.f;
        }
        #pragma unroll
        for (int mt = 0; mt < 3; mt++) {
            int dn = mt * 16 + l16;
            bool ok = dn < NPG;
            float edv = 0.f;
            uint2 c0 = make_uint2(0u, 0u), c1 = make_uint2(0u, 0u);
            if (ok) {
                edv = ed[w * NPG + dn];
                c0 = *(const uint2*)&cnt[dn * 48 + quad * 8];
                if (quad == 0) c1 = *(const uint2*)&cnt[dn * 48 + 32];
            }
            float v0[8], v1[8];
            int cb0[8], cb1[8];
            float pm = -1e30f;
            #pragma unroll
            for (int j = 0; j < 8; j++) {
                cb0[j] = (int)(((j < 4 ? c0.x : c0.y) >> ((j & 3) * 8)) & 0xffu);
                float t0 = esv0[j] + edv;
                v0[j] = t0 > 0.f ? t0 : 0.2f * t0;
                if (cb0[j]) pm = fmaxf(pm, v0[j]);
                cb1[j] = (int)(((j < 4 ? c1.x : c1.y) >> ((j & 3) * 8)) & 0xffu);
                float t1 = esv1[j] + edv;
                v1[j] = t1 > 0.f ? t1 : 0.2f * t1;
                if (cb1[j]) pm = fmaxf(pm, v1[j]);
            }
            pm = fmaxf(pm, __shfl_xor(pm, 16));
            pm = fmaxf(pm, __shfl_xor(pm, 32));
            float e0[8], e1[8], pd = 0.f;
            #pragma unroll
            for (int j = 0; j < 8; j++) {
                e0[j] = cb0[j] ? (float)cb0[j] * __expf(v0[j] - pm) : 0.f;
                e1[j] = cb1[j] ? (float)cb1[j] * __expf(v1[j] - pm) : 0.f;
                pd += e0[j] + e1[j];
            }
            pd += __shfl_xor(pd, 16);
            pd += __shfl_xor(pd, 32);
            float di = ok ? 1.f / pd : 0.f;
            #pragma unroll
            for (int j = 0; j < 8; j++) {
                float a0 = e0[j] * di;
                unsigned short hb0 = f2b(a0);
                ahi[mt][0][j] = (short)hb0;
                alo[mt][0][j] = (short)f2b(a0 - b2f(hb0));
                float a1 = e1[j] * di;
                unsigned short hb1 = f2b(a1);
                ahi[mt][1][j] = (short)hb1;
                alo[mt][1][j] = (short)f2b(a1 - b2f(hb1));
            }
        }
        const floatx4 z = {0.f, 0.f, 0.f, 0.f};
        for (int nt = 0; nt < 8; nt++) {
            const int ch0 = w * 128 + nt * 16;
            bf16x8 b0, b1 = {0,0,0,0,0,0,0,0};
            __builtin_memcpy(&b0, &ht[htoff(ch0 + l16, quad * 8)], 16);
            if (quad == 0) __builtin_memcpy(&b1, &ht[htoff(ch0 + l16, 32)], 16);
            floatx4 acc0 = z, acc1 = z, acc2 = z;
            acc0 = __builtin_amdgcn_mfma_f32_16x16x32_bf16(ahi[0][0], b0, acc0, 0, 0, 0);
            acc1 = __builtin_amdgcn_mfma_f32_16x16x32_bf16(ahi[1][0], b0, acc1, 0, 0, 0);
            acc2 = __builtin_amdgcn_mfma_f32_16x16x32_bf16(ahi[2][0], b0, acc2, 0, 0, 0);
            acc0 = __builtin_amdgcn_mfma_f32_16x16x32_bf16(alo[0][0], b0, acc0, 0, 0, 0);
            acc1 = __builtin_amdgcn_mfma_f32_16x16x32_bf16(alo[1][0], b0, acc1, 0, 0, 0);
            acc2 = __builtin_amdgcn_mfma_f32_16x16x32_bf16(alo[2][0], b0, acc2, 0, 0, 0);
            acc0 = __builtin_amdgcn_mfma_f32_16x16x32_bf16(ahi[0][1], b1, acc0, 0, 0, 0);
            acc1 = __builtin_amdgcn_mfma_f32_16x16x32_bf16(ahi[1][1], b1, acc1, 0, 0, 0);
            acc2 = __builtin_amdgcn_mfma_f32_16x16x32_bf16(ahi[2][1], b1, acc2, 0, 0, 0);
            acc0 = __builtin_amdgcn_mfma_f32_16x16x32_bf16(alo[0][1], b1, acc0, 0, 0, 0);
            acc1 = __builtin_amdgcn_mfma_f32_16x16x32_bf16(alo[1][1], b1, acc1, 0, 0, 0);
            acc2 = __builtin_amdgcn_mfma_f32_16x16x32_bf16(alo[2][1], b1, acc2, 0, 0, 0);
            const int c = ch0 + l16;
            float scl = rsqrtf(bnv[c] + BN_EPS) * bng[c];
            float sft = (bias[c] - bnm[c]) * scl + bnb[c];
            unsigned short* reg = &ht[ch0 * 40];
            #pragma unroll
            for (int mt = 0; mt < 3; mt++) {
                floatx4 a = (mt == 0) ? acc0 : (mt == 1) ? acc1 : acc2;
                #pragma unroll
                for (int rr = 0; rr < 4; rr++) {
                    int dn = mt * 16 + quad * 4 + rr;
                    if (dn < NPG) {
                        float o = a[rr] * scl + sft;
                        o = fmaxf(o, 0.f);
                        reg[dn * 16 + l16] = f2b(o);
                    }
                }
            }
        }
    }
    __syncthreads();
    // ---- coalesced writeback ----
    for (int u = tid; u < NPG * 64; u += 256) {
        int s = u >> 6, c8 = u & 63;
        const unsigned short* reg = &ht[(c8 >> 1) * 16 * 40];
        uint4 v = *(const uint4*)&reg[s * 16 + (c8 & 1) * 8];
        *(uint4*)(Hg + (size_t)s * D0 + c8 * 8) = v;
    }
}

// ---------------------------------------------------------------------------
// Fused GAT (1 head, 128) + bias + BN (no relu) + mean/max pool -> cmb.
// Logits via MFMA on wave 0 (phase 0, overlapped with staging).
// ---------------------------------------------------------------------------
__global__ __launch_bounds__(256)
void gat1_pool_fused_kernel(const unsigned short* __restrict__ H,  // [chunk*40,128]
                            const int* __restrict__ edge,
                            const unsigned short* __restrict__ avpk, // [4][128]
                            const float* __restrict__ bias,
                            const float* __restrict__ bng, const float* __restrict__ bnb,
                            const float* __restrict__ bnm, const float* __restrict__ bnv,
                            float* __restrict__ cmb, int colbase, int g0)
{
    __shared__ __align__(16) unsigned short ht[HID * NPG];  // 10240 B
    __shared__ float es[NPG], ed[NPG];
    __shared__ __align__(16) unsigned char cnt[NPG * 48];
    __shared__ short2 eloc[ESL];
    const int tid = threadIdx.x;
    const int lane = tid & 63, w = tid >> 6;
    const int quad = lane >> 4, l16 = lane & 15;
    const int gg = g0 + blockIdx.x;
    const unsigned short* Hg = H + (size_t)blockIdx.x * NPG * HID;

    for (int i = tid; i < NPG * 48 / 4; i += 256) ((unsigned int*)cnt)[i] = 0u;
    for (int i = tid; i < ESL; i += 256) {
        if (i < EPG) {
            int s  = edge[(size_t)gg * EPG + i] - gg * NPG;
            int dd = edge[(size_t)ETOT + (size_t)gg * EPG + i] - gg * NPG;
            eloc[i] = make_short2((short)s, (short)dd);
        } else {
            short v = (short)(i - EPG);
            eloc[i] = make_short2(v, v);
        }
    }
    for (int u = tid; u < 16 * (NPG / 4); u += 256) {       // 160 units
        int c8 = u & 15, gi = u >> 4;
        const unsigned short* src = Hg + (size_t)(4 * gi) * HID + c8 * 8;
        uint4 v0 = *(const uint4*)(src);
        uint4 v1 = *(const uint4*)(src + HID);
        uint4 v2 = *(const uint4*)(src + 2 * HID);
        uint4 v3 = *(const uint4*)(src + 3 * HID);
        unsigned int a0[4] = {v0.x, v0.y, v0.z, v0.w};
        unsigned int a1[4] = {v1.x, v1.y, v1.z, v1.w};
        unsigned int a2[4] = {v2.x, v2.y, v2.z, v2.w};
        unsigned int a3[4] = {v3.x, v3.y, v3.z, v3.w};
        #pragma unroll
        for (int k = 0; k < 8; k++) {
            const int ws = k >> 1, sh = (k & 1) * 16;
            unsigned int w0 = ((a0[ws] >> sh) & 0xffffu) | (((a1[ws] >> sh) & 0xffffu) << 16);
            unsigned int w1 = ((a2[ws] >> sh) & 0xffffu) | (((a3[ws] >> sh) & 0xffffu) << 16);
            *(uint2*)&ht[htoff(c8 * 8 + k, 4 * gi)] = make_uint2(w0, w1);
        }
    }
    // ---- logits via MFMA (wave 0 only; reads Hg) ----
    if (w == 0) {
        bf16x8 fP[4];
        #pragma unroll
        for (int kk = 0; kk < 4; kk++)
            __builtin_memcpy(&fP[kk],
                avpk + (l16 & 3) * HID + kk * 32 + quad * 8, 16);
        #pragma unroll
        for (int mt = 0; mt < 3; mt++) {
            int node = mt * 16 + l16; if (node >= NPG) node = NPG - 1;
            const unsigned short* hrow = Hg + (size_t)node * HID;
            floatx4 la = {0.f, 0.f, 0.f, 0.f};
            #pragma unroll
            for (int kk = 0; kk < 4; kk++) {
                bf16x8 fQ;
                __builtin_memcpy(&fQ, hrow + kk * 32 + quad * 8, 16);
                la = __builtin_amdgcn_mfma_f32_16x16x32_bf16(fP[kk], fQ, la, 0, 0, 0);
            }
            if (quad == 0) {
                int nd = mt * 16 + l16;
                if (nd < NPG) {
                    es[nd] = la[0] + la[2];
                    ed[nd] = la[1] + la[3];
                }
            }
        }
    }
    __syncthreads();

    for (int e = tid; e < ESL; e += 256) {
        short2 sd = eloc[e];
        atomicAdd((unsigned int*)cnt + ((sd.y * 48 + sd.x) >> 2),
                  1u << ((sd.x & 3) * 8));
    }
    __syncthreads();

    // ---- in-register alpha + MFMA + pool ----
    {
        bf16x8 ahi[3][2], alo[3][2];
        float esv0[8], esv1[8];
        #pragma unroll
        for (int j = 0; j < 8; j++) {
            esv0[j] = es[quad * 8 + j];
            esv1[j] = (quad == 0) ? es[32 + j] : 0.f;
        }
        #pragma unroll
        for (int mt = 0; mt < 3; mt++) {
            int dn = mt * 16 + l16;
            bool ok = dn < NPG;
            float edv = 0.f;
            uint2 c0 = make_uint2(0u, 0u), c1 = make_uint2(0u, 0u);
            if (ok) {
                edv = ed[dn];
                c0 = *(const uint2*)&cnt[dn * 48 + quad * 8];
                if (quad == 0) c1 = *(const uint2*)&cnt[dn * 48 + 32];
            }
            float v0[8], v1[8];
            int cb0[8], cb1[8];
            float pm = -1e30f;
            #pragma unroll
            for (int j = 0; j < 8; j++) {
                cb0[j] = (int)(((j < 4 ? c0.x : c0.y) >> ((j & 3) * 8)) & 0xffu);
                float t0 = esv0[j] + edv;
                v0[j] = t0 > 0.f ? t0 : 0.2f * t0;
                if (cb0[j]) pm = fmaxf(pm, v0[j]);
                cb1[j] = (int)(((j < 4 ? c1.x : c1.y) >> ((j & 3) * 8)) & 0xffu);
                float t1 = esv1[j] + edv;
                v1[j] = t1 > 0.f ? t1 : 0.2f * t1;
                if (cb1[j]) pm = fmaxf(pm, v1[j]);
            }
            pm = fmaxf(pm, __shfl_xor(pm, 16));
            pm = fmaxf(pm, __shfl_xor(pm, 32));
            float e0[8], e1[8], pd = 0.f;
            #pragma unroll
            for (int j = 0; j < 8; j++) {
                e0[j] = cb0[j] ? (float)cb0[j] * __expf(v0[j] - pm) : 0.f;
                e1[j] = cb1[j] ? (float)cb1[j] * __expf(v1[j] - pm) : 0.f;
                pd += e0[j] + e1[j];
            }
            pd += __shfl_xor(pd, 16);
            pd += __shfl_xor(pd, 32);
            float di = ok ? 1.f / pd : 0.f;
            #pragma unroll
            for (int j = 0; j < 8; j++) {
                float a0 = e0[j] * di;
                unsigned short hb0 = f2b(a0);
                ahi[mt][0][j] = (short)hb0;
                alo[mt][0][j] = (short)f2b(a0 - b2f(hb0));
                float a1 = e1[j] * di;
                unsigned short hb1 = f2b(a1);
                ahi[mt][1][j] = (short)hb1;
                alo[mt][1][j] = (short)f2b(a1 - b2f(hb1));
            }
        }
        const floatx4 z = {0.f, 0.f, 0.f, 0.f};
        for (int t2 = 0; t2 < 2; t2++) {
            const int ch0 = (w * 2 + t2) * 16;
            bf16x8 b0, b1 = {0,0,0,0,0,0,0,0};
            __builtin_memcpy(&b0, &ht[htoff(ch0 + l16, quad * 8)], 16);
            if (quad == 0) __builtin_memcpy(&b1, &ht[htoff(ch0 + l16, 32)], 16);
            floatx4 acc0 = z, acc1 = z, acc2 = z;
            acc0 = __builtin_amdgcn_mfma_f32_16x16x32_bf16(ahi[0][0], b0, acc0, 0, 0, 0);
            acc1 = __builtin_amdgcn_mfma_f32_16x16x32_bf16(ahi[1][0], b0, acc1, 0, 0, 0);
            acc2 = __builtin_amdgcn_mfma_f32_16x16x32_bf16(ahi[2][0], b0, acc2, 0, 0, 0);
            acc0 = __builtin_amdgcn_mfma_f32_16x16x32_bf16(alo[0][0], b0, acc0, 0, 0, 0);
            acc1 = __builtin_amdgcn_mfma_f32_16x16x32_bf16(alo[1][0], b0, acc1, 0, 0, 0);
            acc2 = __builtin_amdgcn_mfma_f32_16x16x32_bf16(alo[2][0], b0, acc2, 0, 0, 0);
            acc0 = __builtin_amdgcn_mfma_f32_16x16x32_bf16(ahi[0][1], b1, acc0, 0, 0, 0);
            acc1 = __builtin_amdgcn_mfma_f32_16x16x32_bf16(ahi[1][1], b1, acc1, 0, 0, 0);
            acc2 = __builtin_amdgcn_mfma_f32_16x16x32_bf16(ahi[2][1], b1, acc2, 0, 0, 0);
            acc0 = __builtin_amdgcn_mfma_f32_16x16x32_bf16(alo[0][1], b1, acc0, 0, 0, 0);
            acc1 = __builtin_amdgcn_mfma_f32_16x16x32_bf16(alo[1][1], b1, acc1, 0, 0, 0);
            acc2 = __builtin_amdgcn_mfma_f32_16x16x32_bf16(alo[2][1], b1, acc2, 0, 0, 0);
            const int c = ch0 + l16;
            float scl = rsqrtf(bnv[c] + BN_EPS) * bng[c];
            float sft = (bias[c] - bnm[c]) * scl + bnb[c];
            float psum = 0.f, pmax = -1e30f;
            #pragma unroll
            for (int mt = 0; mt < 3; mt++) {
                floatx4 a = (mt == 0) ? acc0 : (mt == 1) ? acc1 : acc2;
                #pragma unroll
                for (int rr = 0; rr < 4; rr++) {
                    int dn = mt * 16 + quad * 4 + rr;
                    if (dn < NPG) {
                        float o = a[rr] * scl + sft;   // no relu
                        psum += o;
                        pmax = fmaxf(pmax, o);
                    }
                }
            }
            psum += __shfl_xor(psum, 16); psum += __shfl_xor(psum, 32);
            pmax = fmaxf(pmax, __shfl_xor(pmax, 16));
            pmax = fmaxf(pmax, __shfl_xor(pmax, 32));
            if (quad == 0) {
                cmb[(size_t)gg * 512 + colbase + c] = psum * (1.f / NPG);
                cmb[(size_t)gg * 512 + colbase + HID + c] = pmax;
            }
        }
    }
}

// ---------------------------------------------------------------------------
// Fused MFMA MLP (verified round 4): 16 graphs/block, 256 blocks.
// ---------------------------------------------------------------------------
__global__ __launch_bounds__(256)
void mlp_mfma_kernel(const float* __restrict__ cmb, const float* __restrict__ addf,
                     const unsigned short* __restrict__ W0hi, const unsigned short* __restrict__ W0lo,
                     const float* __restrict__ b0, const float* __restrict__ g0v,
                     const float* __restrict__ be0, const float* __restrict__ m0,
                     const float* __restrict__ v0,
                     const unsigned short* __restrict__ W1hi, const unsigned short* __restrict__ W1lo,
                     const float* __restrict__ b1, const float* __restrict__ g1v,
                     const float* __restrict__ be1, const float* __restrict__ m1,
                     const float* __restrict__ v1,
                     const float* __restrict__ W2, const float* __restrict__ b2,
                     float* __restrict__ out)
{
    __shared__ __align__(16) unsigned short a0hi[16 * A0ST], a0lo[16 * A0ST];
    __shared__ __align__(16) unsigned short h1hi[16 * H1ST], h1lo[16 * H1ST];
    __shared__ float h2[16 * H2ST];
    const int tid = threadIdx.x;
    const int lane = tid & 63, w = tid >> 6;
    const int quad = lane >> 4, l16 = lane & 15;
    const int gb = blockIdx.x * 16;

    for (int i = tid; i < 16 * KPM; i += 256) {
        int g = i / KPM, k = i - g * KPM;
        float x = 0.f;
        if (k < 512) x = cmb[(size_t)(gb + g) * 512 + k];
        else if (k < CMB) x = addf[(gb + g) * 8 + (k - 512)];
        unsigned short hb = f2b(x);
        a0hi[g * A0ST + k] = hb;
        a0lo[g * A0ST + k] = f2b(x - b2f(hb));
    }
    __syncthreads();

    {
        floatx4 acc[4];
        #pragma unroll
        for (int ni = 0; ni < 4; ni++) acc[ni] = (floatx4){0.f, 0.f, 0.f, 0.f};
        for (int k0 = 0; k0 < KPM; k0 += 32) {
            bf16x8 fah, fal;
            __builtin_memcpy(&fah, &a0hi[l16 * A0ST + k0 + quad * 8], 16);
            __builtin_memcpy(&fal, &a0lo[l16 * A0ST + k0 + quad * 8], 16);
            #pragma unroll
            for (int ni = 0; ni < 4; ni++) {
                int row = w * 64 + ni * 16 + l16;
                bf16x8 fwh, fwl;
                __builtin_memcpy(&fwh, &W0hi[(size_t)row * KPM + k0 + quad * 8], 16);
                __builtin_memcpy(&fwl, &W0lo[(size_t)row * KPM + k0 + quad * 8], 16);
                acc[ni] = __builtin_amdgcn_mfma_f32_16x16x32_bf16(fwh, fah, acc[ni], 0, 0, 0);
                acc[ni] = __builtin_amdgcn_mfma_f32_16x16x32_bf16(fwh, fal, acc[ni], 0, 0, 0);
                acc[ni] = __builtin_amdgcn_mfma_f32_16x16x32_bf16(fwl, fah, acc[ni], 0, 0, 0);
            }
        }
        #pragma unroll
        for (int ni = 0; ni < 4; ni++) {
            int cbase = w * 64 + ni * 16 + quad * 4;
            unsigned int ph[2], pl[2];
            #pragma unroll
            for (int j = 0; j < 2; j++) {
                unsigned int hh[2], ll[2];
                #pragma unroll
                for (int q = 0; q < 2; q++) {
                    int rr = 2 * j + q, c = cbase + rr;
                    float scl = rsqrtf(v0[c] + BN_EPS) * g0v[c];
                    float val = (acc[ni][rr] + b0[c] - m0[c]) * scl + be0[c];
                    val = fmaxf(val, 0.f);
                    unsigned short hb = f2b(val);
                    hh[q] = hb;
                    ll[q] = f2b(val - b2f(hb));
                }
                ph[j] = hh[0] | (hh[1] << 16);
                pl[j] = ll[0] | (ll[1] << 16);
            }
            *(uint2*)&h1hi[l16 * H1ST + cbase] = make_uint2(ph[0], ph[1]);
            *(uint2*)&h1lo[l16 * H1ST + cbase] = make_uint2(pl[0], pl[1]);
        }
    }
    __syncthreads();

    {
        floatx4 acc[2];
        acc[0] = (floatx4){0.f, 0.f, 0.f, 0.f};
        acc[1] = (floatx4){0.f, 0.f, 0.f, 0.f};
        for (int k0 = 0; k0 < 256; k0 += 32) {
            bf16x8 fah, fal;
            __builtin_memcpy(&fah, &h1hi[l16 * H1ST + k0 + quad * 8], 16);
            __builtin_memcpy(&fal, &h1lo[l16 * H1ST + k0 + quad * 8], 16);
            #pragma unroll
            for (int ni = 0; ni < 2; ni++) {
                int row = w * 32 + ni * 16 + l16;
                bf16x8 fwh, fwl;
                __builtin_memcpy(&fwh, &W1hi[(size_t)row * 256 + k0 + quad * 8], 16);
                __builtin_memcpy(&fwl, &W1lo[(size_t)row * 256 + k0 + quad * 8], 16);
                acc[ni] = __builtin_amdgcn_mfma_f32_16x16x32_bf16(fwh, fah, acc[ni], 0, 0, 0);
                acc[ni] = __builtin_amdgcn_mfma_f32_16x16x32_bf16(fwh, fal, acc[ni], 0, 0, 0);
                acc[ni] = __builtin_amdgcn_mfma_f32_16x16x32_bf16(fwl, fah, acc[ni], 0, 0, 0);
            }
        }
        #pragma unroll
        for (int ni = 0; ni < 2; ni++) {
            #pragma unroll
            for (int rr = 0; rr < 4; rr++) {
                int c = w * 32 + ni * 16 + quad * 4 + rr;
                float scl = rsqrtf(v1[c] + BN_EPS) * g1v[c];
                float val = (acc[ni][rr] + b1[c] - m1[c]) * scl + be1[c];
                h2[l16 * H2ST + c] = fmaxf(val, 0.f);
            }
        }
    }
    __syncthreads();

    {
        int g = tid >> 4, part = tid & 15;
        float s = 0.f;
        #pragma unroll
        for (int j = 0; j < 8; j++)
            s += h2[g * H2ST + part * 8 + j] * W2[part * 8 + j];
        s += __shfl_xor(s, 1); s += __shfl_xor(s, 2);
        s += __shfl_xor(s, 4); s += __shfl_xor(s, 8);
        if (part == 0) out[gb + g] = 1.f / (1.f + __expf(-(s + b2[0])));
    }
}

// ---------------------------------------------------------------------------
extern "C" void kernel_launch(void* const* d_in, const int* in_sizes, int n_in,
                              void* d_out, int out_size, void* d_ws, size_t ws_size,
                              hipStream_t stream)
{
    float* out = (float*)d_out;
    int out_n = out_size < 4096 ? out_size : 4096;

    const float* x_a  = (const float*)d_in[0];
    const int*   edge_a = (const int*)d_in[1];
    const float* x_b  = (const float*)d_in[3];
    const int*   edge_b = (const int*)d_in[4];
    const float* addf = (const float*)d_in[6];
    const float* gW0 = (const float*)d_in[7],  *gb0 = (const float*)d_in[8];
    const float* gas0 = (const float*)d_in[9], *gad0 = (const float*)d_in[10];
    const float* gW1 = (const float*)d_in[11], *gb1 = (const float*)d_in[12];
    const float* gas1 = (const float*)d_in[13], *gad1 = (const float*)d_in[14];
    const float* gW2 = (const float*)d_in[15], *gb2 = (const float*)d_in[16];
    const float* gas2 = (const float*)d_in[17], *gad2 = (const float*)d_in[18];
    const float* bn0g = (const float*)d_in[19], *bn0b = (const float*)d_in[20];
    const float* bn0m = (const float*)d_in[21], *bn0v = (const float*)d_in[22];
    const float* bn1g = (const float*)d_in[23], *bn1b = (const float*)d_in[24];
    const float* bn1m = (const float*)d_in[25], *bn1v = (const float*)d_in[26];
    const float* bn2g = (const float*)d_in[27], *bn2b = (const float*)d_in[28];
    const float* bn2m = (const float*)d_in[29], *bn2v = (const float*)d_in[30];
    const float* mW0 = (const float*)d_in[31], *mb0 = (const float*)d_in[32];
    const float* mg0 = (const float*)d_in[33], *mbe0 = (const float*)d_in[34];
    const float* mm0 = (const float*)d_in[35], *mv0 = (const float*)d_in[36];
    const float* mW1 = (const float*)d_in[37], *mb1 = (const float*)d_in[38];
    const float* mg1 = (const float*)d_in[39], *mbe1 = (const float*)d_in[40];
    const float* mm1 = (const float*)d_in[41], *mv1 = (const float*)d_in[42];
    const float* mW2 = (const float*)d_in[43], *mb2 = (const float*)d_in[44];

    // ---- workspace layout ----
    char* p = (char*)d_ws;
    const size_t CMB_BYTES = (size_t)B_GRAPHS * 512 * sizeof(float);   // 8 MB
    float* cmb = (float*)p; p += CMB_BYTES;
    unsigned short* W0t = (unsigned short*)p; p += (size_t)D0 * KP0 * 2;
    unsigned short* W1t = (unsigned short*)p; p += (size_t)D0 * D0 * 2;
    unsigned short* W2t = (unsigned short*)p; p += (size_t)HID * D0 * 2;
    unsigned short* M0hi = (unsigned short*)p; p += (size_t)256 * KPM * 2;
    unsigned short* M0lo = (unsigned short*)p; p += (size_t)256 * KPM * 2;
    unsigned short* M1hi = (unsigned short*)p; p += (size_t)128 * 256 * 2;
    unsigned short* M1lo = (unsigned short*)p; p += (size_t)128 * 256 * 2;
    unsigned short* AV0 = (unsigned short*)p; p += (size_t)4 * D0 * 2;
    unsigned short* AV1 = (unsigned short*)p; p += (size_t)4 * D0 * 2;
    unsigned short* AV2 = (unsigned short*)p; p += (size_t)4 * HID * 2;
    size_t used = (size_t)(p - (char*)d_ws);
    const size_t PG = 7680ull + 40960ull + 40960ull;   // Xb + B1 + B2
    int chunk = B_GRAPHS;
    while (chunk > 4 && used + (size_t)chunk * PG > ws_size) chunk >>= 1;
    if (used + (size_t)chunk * PG > ws_size) {
        write_code_kernel<<<(out_n + 255) / 256, 256, 0, stream>>>(out, out_n, 500000.f);
        return;
    }
    unsigned short* Xb = (unsigned short*)p; p += (size_t)chunk * 7680;
    unsigned short* B1 = (unsigned short*)p; p += (size_t)chunk * 40960;
    unsigned short* B2 = (unsigned short*)p;

    // ---- weight conversion (once) ----
    convw_kernel<<<(D0 * KP0 + 255) / 256, 256, 0, stream>>>(gW0, W0t, F_IN, D0, KP0);
    convw_kernel<<<(D0 * D0 + 255) / 256, 256, 0, stream>>>(gW1, W1t, D0, D0, D0);
    convw_kernel<<<(HID * D0 + 255) / 256, 256, 0, stream>>>(gW2, W2t, D0, HID, D0);
    convw_hilo_kernel<<<(256 * KPM + 255) / 256, 256, 0, stream>>>(
        mW0, M0hi, M0lo, CMB, 256, KPM);
    convw_hilo_kernel<<<(128 * 256 + 255) / 256, 256, 0, stream>>>(
        mW1, M1hi, M1lo, 256, 128, 256);
    convav_kernel<<<(4 * D0 + 255) / 256, 256, 0, stream>>>(gas0, gad0, AV0, D0);
    convav_kernel<<<(4 * D0 + 255) / 256, 256, 0, stream>>>(gas1, gad1, AV1, D0);
    convav_kernel<<<(4 * HID + 255) / 256, 256, 0, stream>>>(gas2, gad2, AV2, HID);

    for (int drug = 0; drug < 2; drug++) {
        const float* x = drug ? x_b : x_a;
        const int* edge = drug ? edge_b : edge_a;
        int colbase = drug ? 256 : 0;

        for (int g0 = 0; g0 < B_GRAPHS; g0 += chunk) {
            int n = chunk * NPG;
            int gy = (n + 127) / 128;
            // layer 0
            convx_kernel<<<(n * (KP0 / 8) + 255) / 256, 256, 0, stream>>>(
                x + (size_t)g0 * NPG * F_IN, Xb, n);
            gemm_mfma_kernel<<<dim3(D0 / 128, gy), 256, 0, stream>>>(
                Xb, W0t, B1, n, KP0, D0);
            gat4_fused_kernel<<<chunk, 256, 0, stream>>>(
                B1, edge, AV0, gb0, bn0g, bn0b, bn0m, bn0v, g0);
            // layer 1
            gemm_mfma_kernel<<<dim3(D0 / 128, gy), 256, 0, stream>>>(
                B1, W1t, B2, n, D0, D0);
            gat4_fused_kernel<<<chunk, 256, 0, stream>>>(
                B2, edge, AV1, gb1, bn1g, bn1b, bn1m, bn1v, g0);
            // layer 2
            gemm_mfma_kernel<<<dim3(HID / 128, gy), 256, 0, stream>>>(
                B2, W2t, B1, n, D0, HID);
            gat1_pool_fused_kernel<<<chunk, 256, 0, stream>>>(
                B1, edge, AV2, gb2, bn2g, bn2b, bn2m, bn2v,
                cmb, colbase, g0);
        }
    }
    mlp_mfma_kernel<<<B_GRAPHS / 16, 256, 0, stream>>>(
        cmb, addf, M0hi, M0lo, mb0, mg0, mbe0, mm0, mv0,
        M1hi, M1lo, mb1, mg1, mbe1, mm1, mv1, mW2, mb2, out);
}

// Round 13
// 1328.402 us; speedup vs baseline: 1.0344x; 1.0344x over previous
//
#include <hip/hip_runtime.h>
#include <stdint.h>

#define B_GRAPHS 4096
#define NPG 40
#define NTOT (B_GRAPHS * NPG)      // 163840
#define EPG 160
#define ETOT (B_GRAPHS * EPG)      // 655360
#define ESL 200                    // 160 edges + 40 self-loop slots
#define F_IN 78
#define KP0 96                     // F_IN padded to multiple of 32
#define HID 128
#define D0 512
#define CMB 520
#define BN_EPS 1e-5f
#define KPM 544                    // CMB padded to multiple of 32 (17*32)
#define A0ST 552                   // LDS stride for act0 (bank-spread)
#define H1ST 264                   // LDS stride for h1
#define H2ST 132                   // LDS stride for h2 (fp32)

typedef short bf16x8 __attribute__((ext_vector_type(8)));
typedef float floatx4 __attribute__((ext_vector_type(4)));

__device__ inline float b2f(unsigned short u) {
    union { float f; uint32_t i; } v; v.i = ((uint32_t)u) << 16; return v.f;
}
__device__ inline unsigned short f2b(float f) {
    union { float f; uint32_t i; } v; v.f = f;
    uint32_t x = v.i;
    return (unsigned short)((x + 0x7fffu + ((x >> 16) & 1u)) >> 16);
}
__device__ inline float lo16(uint32_t u) {
    union { float f; uint32_t i; } v; v.i = u << 16; return v.f;
}
__device__ inline float hi16(uint32_t u) {
    union { float f; uint32_t i; } v; v.i = u & 0xffff0000u; return v.f;
}
// transposed-h LDS layout: row = channel (stride 40 u16 = 80 B), the five
// 16B chunks of each row are rotated by (ch % 5) to spread banks across rows.
__device__ inline int htoff(int ch, int s) {
    int chunk = s >> 3, within = s & 7;
    return ch * 40 + (((chunk + ch) % 5) << 3) + within;
}
// async global->LDS 16B (wave-uniform LDS base; per-lane global source)
__device__ inline void gl2lds16(const unsigned short* g, unsigned short* l) {
    __builtin_amdgcn_global_load_lds(
        (const __attribute__((address_space(1))) unsigned int*)g,
        (__attribute__((address_space(3))) unsigned int*)l, 16, 0, 0);
}

__global__ __launch_bounds__(256)
void write_code_kernel(float* __restrict__ out, int n, float S)
{
    int i = blockIdx.x * 256 + threadIdx.x;
    if (i < n) out[i] = (i == 0) ? S : 0.f;
}

// ---------------------------------------------------------------------------
// Weight convert: W [K,N] fp32 -> Wt [N,Kp] bf16 (transposed, zero-padded K)
// ---------------------------------------------------------------------------
__global__ __launch_bounds__(256)
void convw_kernel(const float* __restrict__ W, unsigned short* __restrict__ Wt,
                  int K, int N, int Kp)
{
    int t = blockIdx.x * 256 + threadIdx.x;
    if (t >= N * Kp) return;
    int n = t / Kp, k = t - n * Kp;
    Wt[t] = (k < K) ? f2b(W[(size_t)k * N + n]) : 0;
}

// Weight convert, hi/lo split: W [K,N] fp32 -> Whi/Wlo [N,Kp] bf16
__global__ __launch_bounds__(256)
void convw_hilo_kernel(const float* __restrict__ W,
                       unsigned short* __restrict__ Whi,
                       unsigned short* __restrict__ Wlo,
                       int K, int N, int Kp)
{
    int t = blockIdx.x * 256 + threadIdx.x;
    if (t >= N * Kp) return;
    int n = t / Kp, k = t - n * Kp;
    float x = (k < K) ? W[(size_t)k * N + n] : 0.f;
    unsigned short hb = f2b(x);
    Whi[t] = hb;
    Wlo[t] = f2b(x - b2f(hb));
}

// x convert: X [M,78] fp32 -> Xb [M,96] bf16 zero-padded; 8 outputs/thread
__global__ __launch_bounds__(256)
void convx_kernel(const float* __restrict__ X, unsigned short* __restrict__ Xb, int M)
{
    int t = blockIdx.x * 256 + threadIdx.x;
    if (t >= M * (KP0 / 8)) return;
    int r = t / (KP0 / 8), c8 = t - r * (KP0 / 8);
    unsigned int pk[4];
    #pragma unroll
    for (int j = 0; j < 4; j++) {
        int k0 = c8 * 8 + 2 * j, k1 = k0 + 1;
        float x0 = (k0 < F_IN) ? X[(size_t)r * F_IN + k0] : 0.f;
        float x1 = (k1 < F_IN) ? X[(size_t)r * F_IN + k1] : 0.f;
        pk[j] = (unsigned int)f2b(x0) | ((unsigned int)f2b(x1) << 16);
    }
    *(uint4*)&Xb[(size_t)r * KP0 + c8 * 8] = make_uint4(pk[0], pk[1], pk[2], pk[3]);
}

// ---------------------------------------------------------------------------
// MFMA GEMM (BK=32, verified): C[M,N] = A[M,K] @ Bt[N,K]^T. Used for K=96.
// ---------------------------------------------------------------------------
__global__ __launch_bounds__(256)
void gemm_mfma_kernel(const unsigned short* __restrict__ A,
                      const unsigned short* __restrict__ Bt,
                      unsigned short* __restrict__ C,
                      int M, int K, int N)
{
    __shared__ __align__(16) unsigned short As[128 * 32];   // 8 KB
    __shared__ __align__(16) unsigned short Bs[128 * 32];   // 8 KB
    const int tid  = threadIdx.x;
    const int lane = tid & 63, w = tid >> 6;
    const int quad = lane >> 4, l16 = lane & 15;
    const int wm = w >> 1, wn = w & 1;
    // bijective XCD swizzle
    const int nwg  = gridDim.x * gridDim.y;
    const int orig = blockIdx.y * gridDim.x + blockIdx.x;
    const int q = nwg >> 3, r = nwg & 7;
    const int xcd = orig & 7, off = orig >> 3;
    const int swz = (xcd < r ? xcd * (q + 1) : r * (q + 1) + (xcd - r) * q) + off;
    const int row0 = (swz / gridDim.x) * 128, col0 = (swz % gridDim.x) * 128;

    floatx4 acc[4][4];
    #pragma unroll
    for (int mi = 0; mi < 4; mi++)
        #pragma unroll
        for (int ni = 0; ni < 4; ni++)
            acc[mi][ni] = (floatx4){0.f, 0.f, 0.f, 0.f};

    int srow[2], scg[2];
    #pragma unroll
    for (int it = 0; it < 2; it++) {
        int L = it * 4096 + w * 1024 + lane * 16;
        int rr = L >> 6;
        int cp = (L >> 4) & 3;
        srow[it] = rr;
        scg[it]  = cp ^ ((rr >> 1) & 3);
    }

    for (int k0 = 0; k0 < K; k0 += 32) {
        #pragma unroll
        for (int it = 0; it < 2; it++) {
            int ra = row0 + srow[it]; if (ra >= M) ra = M - 1;
            gl2lds16(A + (size_t)ra * K + k0 + scg[it] * 8,
                     As + (it * 4096 + w * 1024) / 2);
            int rb = col0 + srow[it];
            gl2lds16(Bt + (size_t)rb * K + k0 + scg[it] * 8,
                     Bs + (it * 4096 + w * 1024) / 2);
        }
        __syncthreads();

        bf16x8 fA[4], fB[4];
        #pragma unroll
        for (int mi = 0; mi < 4; mi++) {
            int rr = wm * 64 + mi * 16 + l16;
            __builtin_memcpy(&fA[mi], &As[rr * 32 + ((quad ^ ((rr >> 1) & 3)) * 8)], 16);
        }
        #pragma unroll
        for (int ni = 0; ni < 4; ni++) {
            int rr = wn * 64 + ni * 16 + l16;
            __builtin_memcpy(&fB[ni], &Bs[rr * 32 + ((quad ^ ((rr >> 1) & 3)) * 8)], 16);
        }
        #pragma unroll
        for (int mi = 0; mi < 4; mi++)
            #pragma unroll
            for (int ni = 0; ni < 4; ni++)
                acc[mi][ni] = __builtin_amdgcn_mfma_f32_16x16x32_bf16(
                    fB[ni], fA[mi], acc[mi][ni], 0, 0, 0);
        __syncthreads();
    }

    #pragma unroll
    for (int mi = 0; mi < 4; mi++) {
        int row = row0 + wm * 64 + mi * 16 + l16;
        if (row < M) {
            #pragma unroll
            for (int ni = 0; ni < 4; ni++) {
                floatx4 a = acc[mi][ni];
                unsigned int p0 = (unsigned int)f2b(a[0]) | ((unsigned int)f2b(a[1]) << 16);
                unsigned int p1 = (unsigned int)f2b(a[2]) | ((unsigned int)f2b(a[3]) << 16);
                *(uint2*)(C + (size_t)row * N + col0 + wn * 64 + ni * 16 + quad * 4) =
                    make_uint2(p0, p1);
            }
        }
    }
}

// ---------------------------------------------------------------------------
// MFMA GEMM, BK=64: halves barrier-drain count (32 MFMAs per barrier pair).
// LDS 32 KB (still >=2 blocks/CU at VGPR=68 which is the binding limit).
// Requires K % 64 == 0 (used for the K=512 layers). Same XOR-chunk swizzle,
// extended to 8 chunks/row (2-bit mask -> bijective within each 4-chunk half,
// matching the j-indexed fragment reads).
// ---------------------------------------------------------------------------
__global__ __launch_bounds__(256)
void gemm_mfma64_kernel(const unsigned short* __restrict__ A,
                        const unsigned short* __restrict__ Bt,
                        unsigned short* __restrict__ C,
                        int M, int K, int N)
{
    __shared__ __align__(16) unsigned short As[128 * 64];   // 16 KB
    __shared__ __align__(16) unsigned short Bs[128 * 64];   // 16 KB
    const int tid  = threadIdx.x;
    const int lane = tid & 63, w = tid >> 6;
    const int quad = lane >> 4, l16 = lane & 15;
    const int wm = w >> 1, wn = w & 1;
    // bijective XCD swizzle
    const int nwg  = gridDim.x * gridDim.y;
    const int orig = blockIdx.y * gridDim.x + blockIdx.x;
    const int q = nwg >> 3, r = nwg & 7;
    const int xcd = orig & 7, off = orig >> 3;
    const int swz = (xcd < r ? xcd * (q + 1) : r * (q + 1) + (xcd - r) * q) + off;
    const int row0 = (swz / gridDim.x) * 128, col0 = (swz % gridDim.x) * 128;

    floatx4 acc[4][4];
    #pragma unroll
    for (int mi = 0; mi < 4; mi++)
        #pragma unroll
        for (int ni = 0; ni < 4; ni++)
            acc[mi][ni] = (floatx4){0.f, 0.f, 0.f, 0.f};

    // staging: 4 rounds per operand; row = L>>7 (128 B/row), 8 chunks/row
    int srow[4], scg[4];
    #pragma unroll
    for (int it = 0; it < 4; it++) {
        int L = it * 4096 + w * 1024 + lane * 16;
        int rr = L >> 7;
        int cp = (L >> 4) & 7;
        srow[it] = rr;
        scg[it]  = cp ^ ((rr >> 1) & 3);
    }

    for (int k0 = 0; k0 < K; k0 += 64) {
        #pragma unroll
        for (int it = 0; it < 4; it++) {
            int ra = row0 + srow[it]; if (ra >= M) ra = M - 1;
            gl2lds16(A + (size_t)ra * K + k0 + scg[it] * 8,
                     As + (it * 4096 + w * 1024) / 2);
            int rb = col0 + srow[it];
            gl2lds16(Bt + (size_t)rb * K + k0 + scg[it] * 8,
                     Bs + (it * 4096 + w * 1024) / 2);
        }
        __syncthreads();

        #pragma unroll
        for (int j = 0; j < 2; j++) {
            bf16x8 fA[4], fB[4];
            #pragma unroll
            for (int mi = 0; mi < 4; mi++) {
                int rr = wm * 64 + mi * 16 + l16;
                __builtin_memcpy(&fA[mi],
                    &As[rr * 64 + (((j * 4 + quad) ^ ((rr >> 1) & 3)) * 8)], 16);
            }
            #pragma unroll
            for (int ni = 0; ni < 4; ni++) {
                int rr = wn * 64 + ni * 16 + l16;
                __builtin_memcpy(&fB[ni],
                    &Bs[rr * 64 + (((j * 4 + quad) ^ ((rr >> 1) & 3)) * 8)], 16);
            }
            #pragma unroll
            for (int mi = 0; mi < 4; mi++)
                #pragma unroll
                for (int ni = 0; ni < 4; ni++)
                    acc[mi][ni] = __builtin_amdgcn_mfma_f32_16x16x32_bf16(
                        fB[ni], fA[mi], acc[mi][ni], 0, 0, 0);
        }
        __syncthreads();
    }

    #pragma unroll
    for (int mi = 0; mi < 4; mi++) {
        int row = row0 + wm * 64 + mi * 16 + l16;
        if (row < M) {
            #pragma unroll
            for (int ni = 0; ni < 4; ni++) {
                floatx4 a = acc[mi][ni];
                unsigned int p0 = (unsigned int)f2b(a[0]) | ((unsigned int)f2b(a[1]) << 16);
                unsigned int p1 = (unsigned int)f2b(a[2]) | ((unsigned int)f2b(a[3]) << 16);
                *(uint2*)(C + (size_t)row * N + col0 + wn * 64 + ni * 16 + quad * 4) =
                    make_uint2(p0, p1);
            }
        }
    }
}

// ---------------------------------------------------------------------------
// Fused GAT (4 heads x 128, concat 512) + bias + BN + ReLU. In-place on H.
// (verified best: R7/R11, 1338 us)
// ---------------------------------------------------------------------------
__global__ __launch_bounds__(256)
void gat4_fused_kernel(unsigned short* __restrict__ H,     // [chunk*40, 512]
                       const int* __restrict__ edge,
                       const float* __restrict__ avs, const float* __restrict__ avd,
                       const float* __restrict__ bias,
                       const float* __restrict__ bng, const float* __restrict__ bnb,
                       const float* __restrict__ bnm, const float* __restrict__ bnv,
                       int g0)
{
    __shared__ __align__(16) unsigned short ht[D0 * NPG];   // 40960 B [512][40]
    __shared__ float es[4 * NPG], ed[4 * NPG];              // [head][node]
    __shared__ __align__(16) unsigned char cnt[NPG * 48];   // [dn][s]
    __shared__ short2 eloc[ESL];
    const int tid = threadIdx.x;
    const int lane = tid & 63, w = tid >> 6;                // wave = head
    const int quad = lane >> 4, l16 = lane & 15;
    const int gg = g0 + blockIdx.x;
    unsigned short* Hg = H + (size_t)blockIdx.x * NPG * D0;

    // ---- phase 0: init + edge load + transpose-stage ----
    for (int i = tid; i < NPG * 48 / 4; i += 256) ((unsigned int*)cnt)[i] = 0u;
    for (int i = tid; i < ESL; i += 256) {
        if (i < EPG) {
            int s  = edge[(size_t)gg * EPG + i] - gg * NPG;
            int dd = edge[(size_t)ETOT + (size_t)gg * EPG + i] - gg * NPG;
            eloc[i] = make_short2((short)s, (short)dd);
        } else {
            short v = (short)(i - EPG);
            eloc[i] = make_short2(v, v);
        }
    }
    for (int u = tid; u < 64 * (NPG / 4); u += 256) {       // 640 units
        int c8 = u & 63, gi = u >> 6;
        const unsigned short* src = Hg + (size_t)(4 * gi) * D0 + c8 * 8;
        uint4 v0 = *(const uint4*)(src);
        uint4 v1 = *(const uint4*)(src + D0);
        uint4 v2 = *(const uint4*)(src + 2 * D0);
        uint4 v3 = *(const uint4*)(src + 3 * D0);
        unsigned int a0[4] = {v0.x, v0.y, v0.z, v0.w};
        unsigned int a1[4] = {v1.x, v1.y, v1.z, v1.w};
        unsigned int a2[4] = {v2.x, v2.y, v2.z, v2.w};
        unsigned int a3[4] = {v3.x, v3.y, v3.z, v3.w};
        #pragma unroll
        for (int k = 0; k < 8; k++) {
            const int ws = k >> 1, sh = (k & 1) * 16;
            unsigned int w0 = ((a0[ws] >> sh) & 0xffffu) | (((a1[ws] >> sh) & 0xffffu) << 16);
            unsigned int w1 = ((a2[ws] >> sh) & 0xffffu) | (((a3[ws] >> sh) & 0xffffu) << 16);
            *(uint2*)&ht[htoff(c8 * 8 + k, 4 * gi)] = make_uint2(w0, w1);
        }
    }
    __syncthreads();

    // ---- phase 1: logits (wave w = head w) + edge-count build ----
    {
        float as0=0,as1=0,as2=0,as3=0, ad0=0,ad1=0,ad2=0,ad3=0;
        for (int ci = 0; ci < 32; ci++) {
            int c = quad + ci * 4;
            int chv = w * 128 + c;
            uint2 hv = *(const uint2*)&ht[htoff(chv, 4 * l16)];
            float h0 = lo16(hv.x), h1 = hi16(hv.x), h2 = lo16(hv.y), h3 = hi16(hv.y);
            float vs = avs[chv], vd = avd[chv];
            as0 += h0*vs; as1 += h1*vs; as2 += h2*vs; as3 += h3*vs;
            ad0 += h0*vd; ad1 += h1*vd; ad2 += h2*vd; ad3 += h3*vd;
        }
        #define RED4(x) x += __shfl_xor(x, 16); x += __shfl_xor(x, 32);
        RED4(as0) RED4(as1) RED4(as2) RED4(as3)
        RED4(ad0) RED4(ad1) RED4(ad2) RED4(ad3)
        #undef RED4
        if (quad == 0) {
            float rs[4] = {as0, as1, as2, as3};
            float rd[4] = {ad0, ad1, ad2, ad3};
            #pragma unroll
            for (int rr = 0; rr < 4; rr++) {
                int node = 4 * l16 + rr;
                if (node < NPG) { es[w * NPG + node] = rs[rr]; ed[w * NPG + node] = rd[rr]; }
            }
        }
    }
    for (int e = tid; e < ESL; e += 256) {
        short2 sd = eloc[e];
        atomicAdd((unsigned int*)cnt + ((sd.y * 48 + sd.x) >> 2),
                  1u << ((sd.x & 3) * 8));
    }
    __syncthreads();

    // ---- phase 2: in-register alpha (masked max + den via shfl) + MFMA ----
    {
        bf16x8 ahi[3][2], alo[3][2];
        float esv0[8], esv1[8];
        #pragma unroll
        for (int j = 0; j < 8; j++) {
            esv0[j] = es[w * NPG + quad * 8 + j];
            esv1[j] = (quad == 0) ? es[w * NPG + 32 + j] : 0.f;
        }
        #pragma unroll
        for (int mt = 0; mt < 3; mt++) {
            int dn = mt * 16 + l16;
            bool ok = dn < NPG;
            float edv = 0.f;
            uint2 c0 = make_uint2(0u, 0u), c1 = make_uint2(0u, 0u);
            if (ok) {
                edv = ed[w * NPG + dn];
                c0 = *(const uint2*)&cnt[dn * 48 + quad * 8];
                if (quad == 0) c1 = *(const uint2*)&cnt[dn * 48 + 32];
            }
            float v0[8], v1[8];
            int cb0[8], cb1[8];
            float pm = -1e30f;
            #pragma unroll
            for (int j = 0; j < 8; j++) {
                cb0[j] = (int)(((j < 4 ? c0.x : c0.y) >> ((j & 3) * 8)) & 0xffu);
                float t0 = esv0[j] + edv;
                v0[j] = t0 > 0.f ? t0 : 0.2f * t0;
                if (cb0[j]) pm = fmaxf(pm, v0[j]);
                cb1[j] = (int)(((j < 4 ? c1.x : c1.y) >> ((j & 3) * 8)) & 0xffu);
                float t1 = esv1[j] + edv;
                v1[j] = t1 > 0.f ? t1 : 0.2f * t1;
                if (cb1[j]) pm = fmaxf(pm, v1[j]);
            }
            pm = fmaxf(pm, __shfl_xor(pm, 16));
            pm = fmaxf(pm, __shfl_xor(pm, 32));
            float e0[8], e1[8], pd = 0.f;
            #pragma unroll
            for (int j = 0; j < 8; j++) {
                e0[j] = cb0[j] ? (float)cb0[j] * __expf(v0[j] - pm) : 0.f;
                e1[j] = cb1[j] ? (float)cb1[j] * __expf(v1[j] - pm) : 0.f;
                pd += e0[j] + e1[j];
            }
            pd += __shfl_xor(pd, 16);
            pd += __shfl_xor(pd, 32);
            float di = ok ? 1.f / pd : 0.f;
            #pragma unroll
            for (int j = 0; j < 8; j++) {
                float a0 = e0[j] * di;
                unsigned short hb0 = f2b(a0);
                ahi[mt][0][j] = (short)hb0;
                alo[mt][0][j] = (short)f2b(a0 - b2f(hb0));
                float a1 = e1[j] * di;
                unsigned short hb1 = f2b(a1);
                ahi[mt][1][j] = (short)hb1;
                alo[mt][1][j] = (short)f2b(a1 - b2f(hb1));
            }
        }
        const floatx4 z = {0.f, 0.f, 0.f, 0.f};
        for (int nt = 0; nt < 8; nt++) {
            const int ch0 = w * 128 + nt * 16;
            bf16x8 b0, b1 = {0,0,0,0,0,0,0,0};
            __builtin_memcpy(&b0, &ht[htoff(ch0 + l16, quad * 8)], 16);
            if (quad == 0) __builtin_memcpy(&b1, &ht[htoff(ch0 + l16, 32)], 16);
            floatx4 acc0 = z, acc1 = z, acc2 = z;
            acc0 = __builtin_amdgcn_mfma_f32_16x16x32_bf16(ahi[0][0], b0, acc0, 0, 0, 0);
            acc1 = __builtin_amdgcn_mfma_f32_16x16x32_bf16(ahi[1][0], b0, acc1, 0, 0, 0);
            acc2 = __builtin_amdgcn_mfma_f32_16x16x32_bf16(ahi[2][0], b0, acc2, 0, 0, 0);
            acc0 = __builtin_amdgcn_mfma_f32_16x16x32_bf16(alo[0][0], b0, acc0, 0, 0, 0);
            acc1 = __builtin_amdgcn_mfma_f32_16x16x32_bf16(alo[1][0], b0, acc1, 0, 0, 0);
            acc2 = __builtin_amdgcn_mfma_f32_16x16x32_bf16(alo[2][0], b0, acc2, 0, 0, 0);
            acc0 = __builtin_amdgcn_mfma_f32_16x16x32_bf16(ahi[0][1], b1, acc0, 0, 0, 0);
            acc1 = __builtin_amdgcn_mfma_f32_16x16x32_bf16(ahi[1][1], b1, acc1, 0, 0, 0);
            acc2 = __builtin_amdgcn_mfma_f32_16x16x32_bf16(ahi[2][1], b1, acc2, 0, 0, 0);
            acc0 = __builtin_amdgcn_mfma_f32_16x16x32_bf16(alo[0][1], b1, acc0, 0, 0, 0);
            acc1 = __builtin_amdgcn_mfma_f32_16x16x32_bf16(alo[1][1], b1, acc1, 0, 0, 0);
            acc2 = __builtin_amdgcn_mfma_f32_16x16x32_bf16(alo[2][1], b1, acc2, 0, 0, 0);
            const int c = ch0 + l16;
            float scl = rsqrtf(bnv[c] + BN_EPS) * bng[c];
            float sft = (bias[c] - bnm[c]) * scl + bnb[c];
            unsigned short* reg = &ht[ch0 * 40];
            #pragma unroll
            for (int mt = 0; mt < 3; mt++) {
                floatx4 a = (mt == 0) ? acc0 : (mt == 1) ? acc1 : acc2;
                #pragma unroll
                for (int rr = 0; rr < 4; rr++) {
                    int dn = mt * 16 + quad * 4 + rr;
                    if (dn < NPG) {
                        float o = a[rr] * scl + sft;
                        o = fmaxf(o, 0.f);
                        reg[dn * 16 + l16] = f2b(o);
                    }
                }
            }
        }
    }
    __syncthreads();
    // ---- coalesced writeback ----
    for (int u = tid; u < NPG * 64; u += 256) {
        int s = u >> 6, c8 = u & 63;
        const unsigned short* reg = &ht[(c8 >> 1) * 16 * 40];
        uint4 v = *(const uint4*)&reg[s * 16 + (c8 & 1) * 8];
        *(uint4*)(Hg + (size_t)s * D0 + c8 * 8) = v;
    }
}

// ---------------------------------------------------------------------------
// Fused GAT (1 head, 128) + bias + BN (no relu) + mean/max pool -> cmb.
// (verified R7/R11)
// ---------------------------------------------------------------------------
__global__ __launch_bounds__(256)
void gat1_pool_fused_kernel(const unsigned short* __restrict__ H,  // [chunk*40,128]
                            const int* __restrict__ edge,
                            const float* __restrict__ avs, const float* __restrict__ avd,
                            const float* __restrict__ bias,
                            const float* __restrict__ bng, const float* __restrict__ bnb,
                            const float* __restrict__ bnm, const float* __restrict__ bnv,
                            float* __restrict__ cmb, int colbase, int g0)
{
    __shared__ __align__(16) unsigned short ht[HID * NPG];  // 10240 B
    __shared__ float es[NPG], ed[NPG];
    __shared__ __align__(16) unsigned char cnt[NPG * 48];
    __shared__ short2 eloc[ESL];
    const int tid = threadIdx.x;
    const int lane = tid & 63, w = tid >> 6;
    const int quad = lane >> 4, l16 = lane & 15;
    const int gg = g0 + blockIdx.x;
    const unsigned short* Hg = H + (size_t)blockIdx.x * NPG * HID;

    for (int i = tid; i < NPG * 48 / 4; i += 256) ((unsigned int*)cnt)[i] = 0u;
    for (int i = tid; i < ESL; i += 256) {
        if (i < EPG) {
            int s  = edge[(size_t)gg * EPG + i] - gg * NPG;
            int dd = edge[(size_t)ETOT + (size_t)gg * EPG + i] - gg * NPG;
            eloc[i] = make_short2((short)s, (short)dd);
        } else {
            short v = (short)(i - EPG);
            eloc[i] = make_short2(v, v);
        }
    }
    for (int u = tid; u < 16 * (NPG / 4); u += 256) {       // 160 units
        int c8 = u & 15, gi = u >> 4;
        const unsigned short* src = Hg + (size_t)(4 * gi) * HID + c8 * 8;
        uint4 v0 = *(const uint4*)(src);
        uint4 v1 = *(const uint4*)(src + HID);
        uint4 v2 = *(const uint4*)(src + 2 * HID);
        uint4 v3 = *(const uint4*)(src + 3 * HID);
        unsigned int a0[4] = {v0.x, v0.y, v0.z, v0.w};
        unsigned int a1[4] = {v1.x, v1.y, v1.z, v1.w};
        unsigned int a2[4] = {v2.x, v2.y, v2.z, v2.w};
        unsigned int a3[4] = {v3.x, v3.y, v3.z, v3.w};
        #pragma unroll
        for (int k = 0; k < 8; k++) {
            const int ws = k >> 1, sh = (k & 1) * 16;
            unsigned int w0 = ((a0[ws] >> sh) & 0xffffu) | (((a1[ws] >> sh) & 0xffffu) << 16);
            unsigned int w1 = ((a2[ws] >> sh) & 0xffffu) | (((a3[ws] >> sh) & 0xffffu) << 16);
            *(uint2*)&ht[htoff(c8 * 8 + k, 4 * gi)] = make_uint2(w0, w1);
        }
    }
    __syncthreads();

    // logits: wave0 -> es, wave1 -> ed; cnt build (all threads)
    if (w < 2) {
        const float* av = w ? avd : avs;
        float a0=0,a1=0,a2=0,a3=0;
        for (int ci = 0; ci < 32; ci++) {
            int c = quad + ci * 4;
            uint2 hv = *(const uint2*)&ht[htoff(c, 4 * l16)];
            float vc = av[c];
            a0 += lo16(hv.x)*vc; a1 += hi16(hv.x)*vc;
            a2 += lo16(hv.y)*vc; a3 += hi16(hv.y)*vc;
        }
        #define RED4(x) x += __shfl_xor(x, 16); x += __shfl_xor(x, 32);
        RED4(a0) RED4(a1) RED4(a2) RED4(a3)
        #undef RED4
        if (quad == 0) {
            float rv[4] = {a0, a1, a2, a3};
            float* dst = w ? ed : es;
            #pragma unroll
            for (int rr = 0; rr < 4; rr++) {
                int node = 4 * l16 + rr;
                if (node < NPG) dst[node] = rv[rr];
            }
        }
    }
    for (int e = tid; e < ESL; e += 256) {
        short2 sd = eloc[e];
        atomicAdd((unsigned int*)cnt + ((sd.y * 48 + sd.x) >> 2),
                  1u << ((sd.x & 3) * 8));
    }
    __syncthreads();

    // ---- in-register alpha + MFMA + pool ----
    {
        bf16x8 ahi[3][2], alo[3][2];
        float esv0[8], esv1[8];
        #pragma unroll
        for (int j = 0; j < 8; j++) {
            esv0[j] = es[quad * 8 + j];
            esv1[j] = (quad == 0) ? es[32 + j] : 0.f;
        }
        #pragma unroll
        for (int mt = 0; mt < 3; mt++) {
            int dn = mt * 16 + l16;
            bool ok = dn < NPG;
            float edv = 0.f;
            uint2 c0 = make_uint2(0u, 0u), c1 = make_uint2(0u, 0u);
            if (ok) {
                edv = ed[dn];
                c0 = *(const uint2*)&cnt[dn * 48 + quad * 8];
                if (quad == 0) c1 = *(const uint2*)&cnt[dn * 48 + 32];
            }
            float v0[8], v1[8];
            int cb0[8], cb1[8];
            float pm = -1e30f;
            #pragma unroll
            for (int j = 0; j < 8; j++) {
                cb0[j] = (int)(((j < 4 ? c0.x : c0.y) >> ((j & 3) * 8)) & 0xffu);
                float t0 = esv0[j] + edv;
                v0[j] = t0 > 0.f ? t0 : 0.2f * t0;
                if (cb0[j]) pm = fmaxf(pm, v0[j]);
                cb1[j] = (int)(((j < 4 ? c1.x : c1.y) >> ((j & 3) * 8)) & 0xffu);
                float t1 = esv1[j] + edv;
                v1[j] = t1 > 0.f ? t1 : 0.2f * t1;
                if (cb1[j]) pm = fmaxf(pm, v1[j]);
            }
            pm = fmaxf(pm, __shfl_xor(pm, 16));
            pm = fmaxf(pm, __shfl_xor(pm, 32));
            float e0[8], e1[8], pd = 0.f;
            #pragma unroll
            for (int j = 0; j < 8; j++) {
                e0[j] = cb0[j] ? (float)cb0[j] * __expf(v0[j] - pm) : 0.f;
                e1[j] = cb1[j] ? (float)cb1[j] * __expf(v1[j] - pm) : 0.f;
                pd += e0[j] + e1[j];
            }
            pd += __shfl_xor(pd, 16);
            pd += __shfl_xor(pd, 32);
            float di = ok ? 1.f / pd : 0.f;
            #pragma unroll
            for (int j = 0; j < 8; j++) {
                float a0 = e0[j] * di;
                unsigned short hb0 = f2b(a0);
                ahi[mt][0][j] = (short)hb0;
                alo[mt][0][j] = (short)f2b(a0 - b2f(hb0));
                float a1 = e1[j] * di;
                unsigned short hb1 = f2b(a1);
                ahi[mt][1][j] = (short)hb1;
                alo[mt][1][j] = (short)f2b(a1 - b2f(hb1));
            }
        }
        const floatx4 z = {0.f, 0.f, 0.f, 0.f};
        for (int t2 = 0; t2 < 2; t2++) {
            const int ch0 = (w * 2 + t2) * 16;
            bf16x8 b0, b1 = {0,0,0,0,0,0,0,0};
            __builtin_memcpy(&b0, &ht[htoff(ch0 + l16, quad * 8)], 16);
            if (quad == 0) __builtin_memcpy(&b1, &ht[htoff(ch0 + l16, 32)], 16);
            floatx4 acc0 = z, acc1 = z, acc2 = z;
            acc0 = __builtin_amdgcn_mfma_f32_16x16x32_bf16(ahi[0][0], b0, acc0, 0, 0, 0);
            acc1 = __builtin_amdgcn_mfma_f32_16x16x32_bf16(ahi[1][0], b0, acc1, 0, 0, 0);
            acc2 = __builtin_amdgcn_mfma_f32_16x16x32_bf16(ahi[2][0], b0, acc2, 0, 0, 0);
            acc0 = __builtin_amdgcn_mfma_f32_16x16x32_bf16(alo[0][0], b0, acc0, 0, 0, 0);
            acc1 = __builtin_amdgcn_mfma_f32_16x16x32_bf16(alo[1][0], b0, acc1, 0, 0, 0);
            acc2 = __builtin_amdgcn_mfma_f32_16x16x32_bf16(alo[2][0], b0, acc2, 0, 0, 0);
            acc0 = __builtin_amdgcn_mfma_f32_16x16x32_bf16(ahi[0][1], b1, acc0, 0, 0, 0);
            acc1 = __builtin_amdgcn_mfma_f32_16x16x32_bf16(ahi[1][1], b1, acc1, 0, 0, 0);
            acc2 = __builtin_amdgcn_mfma_f32_16x16x32_bf16(ahi[2][1], b1, acc2, 0, 0, 0);
            acc0 = __builtin_amdgcn_mfma_f32_16x16x32_bf16(alo[0][1], b1, acc0, 0, 0, 0);
            acc1 = __builtin_amdgcn_mfma_f32_16x16x32_bf16(alo[1][1], b1, acc1, 0, 0, 0);
            acc2 = __builtin_amdgcn_mfma_f32_16x16x32_bf16(alo[2][1], b1, acc2, 0, 0, 0);
            const int c = ch0 + l16;
            float scl = rsqrtf(bnv[c] + BN_EPS) * bng[c];
            float sft = (bias[c] - bnm[c]) * scl + bnb[c];
            float psum = 0.f, pmax = -1e30f;
            #pragma unroll
            for (int mt = 0; mt < 3; mt++) {
                floatx4 a = (mt == 0) ? acc0 : (mt == 1) ? acc1 : acc2;
                #pragma unroll
                for (int rr = 0; rr < 4; rr++) {
                    int dn = mt * 16 + quad * 4 + rr;
                    if (dn < NPG) {
                        float o = a[rr] * scl + sft;   // no relu
                        psum += o;
                        pmax = fmaxf(pmax, o);
                    }
                }
            }
            psum += __shfl_xor(psum, 16); psum += __shfl_xor(psum, 32);
            pmax = fmaxf(pmax, __shfl_xor(pmax, 16));
            pmax = fmaxf(pmax, __shfl_xor(pmax, 32));
            if (quad == 0) {
                cmb[(size_t)gg * 512 + colbase + c] = psum * (1.f / NPG);
                cmb[(size_t)gg * 512 + colbase + HID + c] = pmax;
            }
        }
    }
}

// ---------------------------------------------------------------------------
// Fused MFMA MLP (verified round 4): 16 graphs/block, 256 blocks.
// ---------------------------------------------------------------------------
__global__ __launch_bounds__(256)
void mlp_mfma_kernel(const float* __restrict__ cmb, const float* __restrict__ addf,
                     const unsigned short* __restrict__ W0hi, const unsigned short* __restrict__ W0lo,
                     const float* __restrict__ b0, const float* __restrict__ g0v,
                     const float* __restrict__ be0, const float* __restrict__ m0,
                     const float* __restrict__ v0,
                     const unsigned short* __restrict__ W1hi, const unsigned short* __restrict__ W1lo,
                     const float* __restrict__ b1, const float* __restrict__ g1v,
                     const float* __restrict__ be1, const float* __restrict__ m1,
                     const float* __restrict__ v1,
                     const float* __restrict__ W2, const float* __restrict__ b2,
                     float* __restrict__ out)
{
    __shared__ __align__(16) unsigned short a0hi[16 * A0ST], a0lo[16 * A0ST];
    __shared__ __align__(16) unsigned short h1hi[16 * H1ST], h1lo[16 * H1ST];
    __shared__ float h2[16 * H2ST];
    const int tid = threadIdx.x;
    const int lane = tid & 63, w = tid >> 6;
    const int quad = lane >> 4, l16 = lane & 15;
    const int gb = blockIdx.x * 16;

    for (int i = tid; i < 16 * KPM; i += 256) {
        int g = i / KPM, k = i - g * KPM;
        float x = 0.f;
        if (k < 512) x = cmb[(size_t)(gb + g) * 512 + k];
        else if (k < CMB) x = addf[(gb + g) * 8 + (k - 512)];
        unsigned short hb = f2b(x);
        a0hi[g * A0ST + k] = hb;
        a0lo[g * A0ST + k] = f2b(x - b2f(hb));
    }
    __syncthreads();

    {
        floatx4 acc[4];
        #pragma unroll
        for (int ni = 0; ni < 4; ni++) acc[ni] = (floatx4){0.f, 0.f, 0.f, 0.f};
        for (int k0 = 0; k0 < KPM; k0 += 32) {
            bf16x8 fah, fal;
            __builtin_memcpy(&fah, &a0hi[l16 * A0ST + k0 + quad * 8], 16);
            __builtin_memcpy(&fal, &a0lo[l16 * A0ST + k0 + quad * 8], 16);
            #pragma unroll
            for (int ni = 0; ni < 4; ni++) {
                int row = w * 64 + ni * 16 + l16;
                bf16x8 fwh, fwl;
                __builtin_memcpy(&fwh, &W0hi[(size_t)row * KPM + k0 + quad * 8], 16);
                __builtin_memcpy(&fwl, &W0lo[(size_t)row * KPM + k0 + quad * 8], 16);
                acc[ni] = __builtin_amdgcn_mfma_f32_16x16x32_bf16(fwh, fah, acc[ni], 0, 0, 0);
                acc[ni] = __builtin_amdgcn_mfma_f32_16x16x32_bf16(fwh, fal, acc[ni], 0, 0, 0);
                acc[ni] = __builtin_amdgcn_mfma_f32_16x16x32_bf16(fwl, fah, acc[ni], 0, 0, 0);
            }
        }
        #pragma unroll
        for (int ni = 0; ni < 4; ni++) {
            int cbase = w * 64 + ni * 16 + quad * 4;
            unsigned int ph[2], pl[2];
            #pragma unroll
            for (int j = 0; j < 2; j++) {
                unsigned int hh[2], ll[2];
                #pragma unroll
                for (int q = 0; q < 2; q++) {
                    int rr = 2 * j + q, c = cbase + rr;
                    float scl = rsqrtf(v0[c] + BN_EPS) * g0v[c];
                    float val = (acc[ni][rr] + b0[c] - m0[c]) * scl + be0[c];
                    val = fmaxf(val, 0.f);
                    unsigned short hb = f2b(val);
                    hh[q] = hb;
                    ll[q] = f2b(val - b2f(hb));
                }
                ph[j] = hh[0] | (hh[1] << 16);
                pl[j] = ll[0] | (ll[1] << 16);
            }
            *(uint2*)&h1hi[l16 * H1ST + cbase] = make_uint2(ph[0], ph[1]);
            *(uint2*)&h1lo[l16 * H1ST + cbase] = make_uint2(pl[0], pl[1]);
        }
    }
    __syncthreads();

    {
        floatx4 acc[2];
        acc[0] = (floatx4){0.f, 0.f, 0.f, 0.f};
        acc[1] = (floatx4){0.f, 0.f, 0.f, 0.f};
        for (int k0 = 0; k0 < 256; k0 += 32) {
            bf16x8 fah, fal;
            __builtin_memcpy(&fah, &h1hi[l16 * H1ST + k0 + quad * 8], 16);
            __builtin_memcpy(&fal, &h1lo[l16 * H1ST + k0 + quad * 8], 16);
            #pragma unroll
            for (int ni = 0; ni < 2; ni++) {
                int row = w * 32 + ni * 16 + l16;
                bf16x8 fwh, fwl;
                __builtin_memcpy(&fwh, &W1hi[(size_t)row * 256 + k0 + quad * 8], 16);
                __builtin_memcpy(&fwl, &W1lo[(size_t)row * 256 + k0 + quad * 8], 16);
                acc[ni] = __builtin_amdgcn_mfma_f32_16x16x32_bf16(fwh, fah, acc[ni], 0, 0, 0);
                acc[ni] = __builtin_amdgcn_mfma_f32_16x16x32_bf16(fwh, fal, acc[ni], 0, 0, 0);
                acc[ni] = __builtin_amdgcn_mfma_f32_16x16x32_bf16(fwl, fah, acc[ni], 0, 0, 0);
            }
        }
        #pragma unroll
        for (int ni = 0; ni < 2; ni++) {
            #pragma unroll
            for (int rr = 0; rr < 4; rr++) {
                int c = w * 32 + ni * 16 + quad * 4 + rr;
                float scl = rsqrtf(v1[c] + BN_EPS) * g1v[c];
                float val = (acc[ni][rr] + b1[c] - m1[c]) * scl + be1[c];
                h2[l16 * H2ST + c] = fmaxf(val, 0.f);
            }
        }
    }
    __syncthreads();

    {
        int g = tid >> 4, part = tid & 15;
        float s = 0.f;
        #pragma unroll
        for (int j = 0; j < 8; j++)
            s += h2[g * H2ST + part * 8 + j] * W2[part * 8 + j];
        s += __shfl_xor(s, 1); s += __shfl_xor(s, 2);
        s += __shfl_xor(s, 4); s += __shfl_xor(s, 8);
        if (part == 0) out[gb + g] = 1.f / (1.f + __expf(-(s + b2[0])));
    }
}

// ---------------------------------------------------------------------------
extern "C" void kernel_launch(void* const* d_in, const int* in_sizes, int n_in,
                              void* d_out, int out_size, void* d_ws, size_t ws_size,
                              hipStream_t stream)
{
    float* out = (float*)d_out;
    int out_n = out_size < 4096 ? out_size : 4096;

    const float* x_a  = (const float*)d_in[0];
    const int*   edge_a = (const int*)d_in[1];
    const float* x_b  = (const float*)d_in[3];
    const int*   edge_b = (const int*)d_in[4];
    const float* addf = (const float*)d_in[6];
    const float* gW0 = (const float*)d_in[7],  *gb0 = (const float*)d_in[8];
    const float* gas0 = (const float*)d_in[9], *gad0 = (const float*)d_in[10];
    const float* gW1 = (const float*)d_in[11], *gb1 = (const float*)d_in[12];
    const float* gas1 = (const float*)d_in[13], *gad1 = (const float*)d_in[14];
    const float* gW2 = (const float*)d_in[15], *gb2 = (const float*)d_in[16];
    const float* gas2 = (const float*)d_in[17], *gad2 = (const float*)d_in[18];
    const float* bn0g = (const float*)d_in[19], *bn0b = (const float*)d_in[20];
    const float* bn0m = (const float*)d_in[21], *bn0v = (const float*)d_in[22];
    const float* bn1g = (const float*)d_in[23], *bn1b = (const float*)d_in[24];
    const float* bn1m = (const float*)d_in[25], *bn1v = (const float*)d_in[26];
    const float* bn2g = (const float*)d_in[27], *bn2b = (const float*)d_in[28];
    const float* bn2m = (const float*)d_in[29], *bn2v = (const float*)d_in[30];
    const float* mW0 = (const float*)d_in[31], *mb0 = (const float*)d_in[32];
    const float* mg0 = (const float*)d_in[33], *mbe0 = (const float*)d_in[34];
    const float* mm0 = (const float*)d_in[35], *mv0 = (const float*)d_in[36];
    const float* mW1 = (const float*)d_in[37], *mb1 = (const float*)d_in[38];
    const float* mg1 = (const float*)d_in[39], *mbe1 = (const float*)d_in[40];
    const float* mm1 = (const float*)d_in[41], *mv1 = (const float*)d_in[42];
    const float* mW2 = (const float*)d_in[43], *mb2 = (const float*)d_in[44];

    // ---- workspace layout ----
    char* p = (char*)d_ws;
    const size_t CMB_BYTES = (size_t)B_GRAPHS * 512 * sizeof(float);   // 8 MB
    float* cmb = (float*)p; p += CMB_BYTES;
    unsigned short* W0t = (unsigned short*)p; p += (size_t)D0 * KP0 * 2;
    unsigned short* W1t = (unsigned short*)p; p += (size_t)D0 * D0 * 2;
    unsigned short* W2t = (unsigned short*)p; p += (size_t)HID * D0 * 2;
    unsigned short* M0hi = (unsigned short*)p; p += (size_t)256 * KPM * 2;
    unsigned short* M0lo = (unsigned short*)p; p += (size_t)256 * KPM * 2;
    unsigned short* M1hi = (unsigned short*)p; p += (size_t)128 * 256 * 2;
    unsigned short* M1lo = (unsigned short*)p; p += (size_t)128 * 256 * 2;
    size_t used = (size_t)(p - (char*)d_ws);
    const size_t PG = 7680ull + 40960ull + 40960ull;   // Xb + B1 + B2
    int chunk = B_GRAPHS;
    while (chunk > 4 && used + (size_t)chunk * PG > ws_size) chunk >>= 1;
    if (used + (size_t)chunk * PG > ws_size) {
        write_code_kernel<<<(out_n + 255) / 256, 256, 0, stream>>>(out, out_n, 500000.f);
        return;
    }
    unsigned short* Xb = (unsigned short*)p; p += (size_t)chunk * 7680;
    unsigned short* B1 = (unsigned short*)p; p += (size_t)chunk * 40960;
    unsigned short* B2 = (unsigned short*)p;

    // ---- weight conversion (once) ----
    convw_kernel<<<(D0 * KP0 + 255) / 256, 256, 0, stream>>>(gW0, W0t, F_IN, D0, KP0);
    convw_kernel<<<(D0 * D0 + 255) / 256, 256, 0, stream>>>(gW1, W1t, D0, D0, D0);
    convw_kernel<<<(HID * D0 + 255) / 256, 256, 0, stream>>>(gW2, W2t, D0, HID, D0);
    convw_hilo_kernel<<<(256 * KPM + 255) / 256, 256, 0, stream>>>(
        mW0, M0hi, M0lo, CMB, 256, KPM);
    convw_hilo_kernel<<<(128 * 256 + 255) / 256, 256, 0, stream>>>(
        mW1, M1hi, M1lo, 256, 128, 256);

    for (int drug = 0; drug < 2; drug++) {
        const float* x = drug ? x_b : x_a;
        const int* edge = drug ? edge_b : edge_a;
        int colbase = drug ? 256 : 0;

        for (int g0 = 0; g0 < B_GRAPHS; g0 += chunk) {
            int n = chunk * NPG;
            int gy = (n + 127) / 128;
            // layer 0 (K=96 -> BK=32 kernel)
            convx_kernel<<<(n * (KP0 / 8) + 255) / 256, 256, 0, stream>>>(
                x + (size_t)g0 * NPG * F_IN, Xb, n);
            gemm_mfma_kernel<<<dim3(D0 / 128, gy), 256, 0, stream>>>(
                Xb, W0t, B1, n, KP0, D0);
            gat4_fused_kernel<<<chunk, 256, 0, stream>>>(
                B1, edge, gas0, gad0, gb0, bn0g, bn0b, bn0m, bn0v, g0);
            // layer 1 (K=512 -> BK=64 kernel)
            gemm_mfma64_kernel<<<dim3(D0 / 128, gy), 256, 0, stream>>>(
                B1, W1t, B2, n, D0, D0);
            gat4_fused_kernel<<<chunk, 256, 0, stream>>>(
                B2, edge, gas1, gad1, gb1, bn1g, bn1b, bn1m, bn1v, g0);
            // layer 2 (K=512 -> BK=64 kernel)
            gemm_mfma64_kernel<<<dim3(HID / 128, gy), 256, 0, stream>>>(
                B2, W2t, B1, n, D0, HID);
            gat1_pool_fused_kernel<<<chunk, 256, 0, stream>>>(
                B1, edge, gas2, gad2, gb2, bn2g, bn2b, bn2m, bn2v,
                cmb, colbase, g0);
        }
    }
    mlp_mfma_kernel<<<B_GRAPHS / 16, 256, 0, stream>>>(
        cmb, addf, M0hi, M0lo, mb0, mg0, mbe0, mm0, mv0,
        M1hi, M1lo, mb1, mg1, mbe1, mm1, mv1, mW2, mb2, out);
}

// Round 14
// 1279.536 us; speedup vs baseline: 1.0739x; 1.0382x over previous
//
#include <hip/hip_runtime.h>
#include <stdint.h>

#define B_GRAPHS 4096
#define NPG 40
#define NTOT (B_GRAPHS * NPG)      // 163840
#define EPG 160
#define ETOT (B_GRAPHS * EPG)      // 655360
#define ESL 200                    // 160 edges + 40 self-loop slots
#define F_IN 78
#define KP0 96                     // F_IN padded to multiple of 32
#define HID 128
#define D0 512
#define CMB 520
#define BN_EPS 1e-5f
#define KPM 544                    // CMB padded to multiple of 32 (17*32)
#define A0ST 552                   // LDS stride for act0 (bank-spread)
#define H1ST 264                   // LDS stride for h1
#define H2ST 132                   // LDS stride for h2 (fp32)

typedef short bf16x8 __attribute__((ext_vector_type(8)));
typedef float floatx4 __attribute__((ext_vector_type(4)));

__device__ inline float b2f(unsigned short u) {
    union { float f; uint32_t i; } v; v.i = ((uint32_t)u) << 16; return v.f;
}
__device__ inline unsigned short f2b(float f) {
    union { float f; uint32_t i; } v; v.f = f;
    uint32_t x = v.i;
    return (unsigned short)((x + 0x7fffu + ((x >> 16) & 1u)) >> 16);
}
__device__ inline float lo16(uint32_t u) {
    union { float f; uint32_t i; } v; v.i = u << 16; return v.f;
}
__device__ inline float hi16(uint32_t u) {
    union { float f; uint32_t i; } v; v.i = u & 0xffff0000u; return v.f;
}
// transposed-h LDS layout: row = channel (stride 40 u16 = 80 B), the five
// 16B chunks of each row are rotated by (ch % 5) to spread banks across rows.
__device__ inline int htoff(int ch, int s) {
    int chunk = s >> 3, within = s & 7;
    return ch * 40 + (((chunk + ch) % 5) << 3) + within;
}
// async global->LDS 16B (wave-uniform LDS base; per-lane global source)
__device__ inline void gl2lds16(const unsigned short* g, unsigned short* l) {
    __builtin_amdgcn_global_load_lds(
        (const __attribute__((address_space(1))) unsigned int*)g,
        (__attribute__((address_space(3))) unsigned int*)l, 16, 0, 0);
}

__global__ __launch_bounds__(256)
void write_code_kernel(float* __restrict__ out, int n, float S)
{
    int i = blockIdx.x * 256 + threadIdx.x;
    if (i < n) out[i] = (i == 0) ? S : 0.f;
}

// ---------------------------------------------------------------------------
// Weight convert: W [K,N] fp32 -> Wt [N,Kp] bf16 (transposed, zero-padded K)
// ---------------------------------------------------------------------------
__global__ __launch_bounds__(256)
void convw_kernel(const float* __restrict__ W, unsigned short* __restrict__ Wt,
                  int K, int N, int Kp)
{
    int t = blockIdx.x * 256 + threadIdx.x;
    if (t >= N * Kp) return;
    int n = t / Kp, k = t - n * Kp;
    Wt[t] = (k < K) ? f2b(W[(size_t)k * N + n]) : 0;
}

// Weight convert, hi/lo split: W [K,N] fp32 -> Whi/Wlo [N,Kp] bf16
__global__ __launch_bounds__(256)
void convw_hilo_kernel(const float* __restrict__ W,
                       unsigned short* __restrict__ Whi,
                       unsigned short* __restrict__ Wlo,
                       int K, int N, int Kp)
{
    int t = blockIdx.x * 256 + threadIdx.x;
    if (t >= N * Kp) return;
    int n = t / Kp, k = t - n * Kp;
    float x = (k < K) ? W[(size_t)k * N + n] : 0.f;
    unsigned short hb = f2b(x);
    Whi[t] = hb;
    Wlo[t] = f2b(x - b2f(hb));
}

// x convert: X [M,78] fp32 -> Xb [M,96] bf16 zero-padded; 8 outputs/thread
__global__ __launch_bounds__(256)
void convx_kernel(const float* __restrict__ X, unsigned short* __restrict__ Xb, int M)
{
    int t = blockIdx.x * 256 + threadIdx.x;
    if (t >= M * (KP0 / 8)) return;
    int r = t / (KP0 / 8), c8 = t - r * (KP0 / 8);
    unsigned int pk[4];
    #pragma unroll
    for (int j = 0; j < 4; j++) {
        int k0 = c8 * 8 + 2 * j, k1 = k0 + 1;
        float x0 = (k0 < F_IN) ? X[(size_t)r * F_IN + k0] : 0.f;
        float x1 = (k1 < F_IN) ? X[(size_t)r * F_IN + k1] : 0.f;
        pk[j] = (unsigned int)f2b(x0) | ((unsigned int)f2b(x1) << 16);
    }
    *(uint4*)&Xb[(size_t)r * KP0 + c8 * 8] = make_uint4(pk[0], pk[1], pk[2], pk[3]);
}

// ---------------------------------------------------------------------------
// MFMA GEMM (BK=32, verified): C[M,N] = A[M,K] @ Bt[N,K]^T. Used for K=96.
// ---------------------------------------------------------------------------
__global__ __launch_bounds__(256)
void gemm_mfma_kernel(const unsigned short* __restrict__ A,
                      const unsigned short* __restrict__ Bt,
                      unsigned short* __restrict__ C,
                      int M, int K, int N)
{
    __shared__ __align__(16) unsigned short As[128 * 32];   // 8 KB
    __shared__ __align__(16) unsigned short Bs[128 * 32];   // 8 KB
    const int tid  = threadIdx.x;
    const int lane = tid & 63, w = tid >> 6;
    const int quad = lane >> 4, l16 = lane & 15;
    const int wm = w >> 1, wn = w & 1;
    // bijective XCD swizzle
    const int nwg  = gridDim.x * gridDim.y;
    const int orig = blockIdx.y * gridDim.x + blockIdx.x;
    const int q = nwg >> 3, r = nwg & 7;
    const int xcd = orig & 7, off = orig >> 3;
    const int swz = (xcd < r ? xcd * (q + 1) : r * (q + 1) + (xcd - r) * q) + off;
    const int row0 = (swz / gridDim.x) * 128, col0 = (swz % gridDim.x) * 128;

    floatx4 acc[4][4];
    #pragma unroll
    for (int mi = 0; mi < 4; mi++)
        #pragma unroll
        for (int ni = 0; ni < 4; ni++)
            acc[mi][ni] = (floatx4){0.f, 0.f, 0.f, 0.f};

    int srow[2], scg[2];
    #pragma unroll
    for (int it = 0; it < 2; it++) {
        int L = it * 4096 + w * 1024 + lane * 16;
        int rr = L >> 6;
        int cp = (L >> 4) & 3;
        srow[it] = rr;
        scg[it]  = cp ^ ((rr >> 1) & 3);
    }

    for (int k0 = 0; k0 < K; k0 += 32) {
        #pragma unroll
        for (int it = 0; it < 2; it++) {
            int ra = row0 + srow[it]; if (ra >= M) ra = M - 1;
            gl2lds16(A + (size_t)ra * K + k0 + scg[it] * 8,
                     As + (it * 4096 + w * 1024) / 2);
            int rb = col0 + srow[it];
            gl2lds16(Bt + (size_t)rb * K + k0 + scg[it] * 8,
                     Bs + (it * 4096 + w * 1024) / 2);
        }
        __syncthreads();

        bf16x8 fA[4], fB[4];
        #pragma unroll
        for (int mi = 0; mi < 4; mi++) {
            int rr = wm * 64 + mi * 16 + l16;
            __builtin_memcpy(&fA[mi], &As[rr * 32 + ((quad ^ ((rr >> 1) & 3)) * 8)], 16);
        }
        #pragma unroll
        for (int ni = 0; ni < 4; ni++) {
            int rr = wn * 64 + ni * 16 + l16;
            __builtin_memcpy(&fB[ni], &Bs[rr * 32 + ((quad ^ ((rr >> 1) & 3)) * 8)], 16);
        }
        #pragma unroll
        for (int mi = 0; mi < 4; mi++)
            #pragma unroll
            for (int ni = 0; ni < 4; ni++)
                acc[mi][ni] = __builtin_amdgcn_mfma_f32_16x16x32_bf16(
                    fB[ni], fA[mi], acc[mi][ni], 0, 0, 0);
        __syncthreads();
    }

    #pragma unroll
    for (int mi = 0; mi < 4; mi++) {
        int row = row0 + wm * 64 + mi * 16 + l16;
        if (row < M) {
            #pragma unroll
            for (int ni = 0; ni < 4; ni++) {
                floatx4 a = acc[mi][ni];
                unsigned int p0 = (unsigned int)f2b(a[0]) | ((unsigned int)f2b(a[1]) << 16);
                unsigned int p1 = (unsigned int)f2b(a[2]) | ((unsigned int)f2b(a[3]) << 16);
                *(uint2*)(C + (size_t)row * N + col0 + wn * 64 + ni * 16 + quad * 4) =
                    make_uint2(p0, p1);
            }
        }
    }
}

// ---------------------------------------------------------------------------
// MFMA GEMM, BK=64 (verified R13, +15% over BK=32): 32 MFMAs per barrier pair.
// FIX (R14): 3-bit per-row chunk XOR (rr & 7). At 128 B row stride, bank =
// f(chunk slot) only, so the old 2-bit mask left a 4-way conflict (5.2M
// counts in R13). 3-bit mask spreads 16 fragment rows over all 8 chunk
// slots -> 2-way = free. Bijective per row; staging source uses same XOR.
// ---------------------------------------------------------------------------
__global__ __launch_bounds__(256)
void gemm_mfma64_kernel(const unsigned short* __restrict__ A,
                        const unsigned short* __restrict__ Bt,
                        unsigned short* __restrict__ C,
                        int M, int K, int N)
{
    __shared__ __align__(16) unsigned short As[128 * 64];   // 16 KB
    __shared__ __align__(16) unsigned short Bs[128 * 64];   // 16 KB
    const int tid  = threadIdx.x;
    const int lane = tid & 63, w = tid >> 6;
    const int quad = lane >> 4, l16 = lane & 15;
    const int wm = w >> 1, wn = w & 1;
    // bijective XCD swizzle
    const int nwg  = gridDim.x * gridDim.y;
    const int orig = blockIdx.y * gridDim.x + blockIdx.x;
    const int q = nwg >> 3, r = nwg & 7;
    const int xcd = orig & 7, off = orig >> 3;
    const int swz = (xcd < r ? xcd * (q + 1) : r * (q + 1) + (xcd - r) * q) + off;
    const int row0 = (swz / gridDim.x) * 128, col0 = (swz % gridDim.x) * 128;

    floatx4 acc[4][4];
    #pragma unroll
    for (int mi = 0; mi < 4; mi++)
        #pragma unroll
        for (int ni = 0; ni < 4; ni++)
            acc[mi][ni] = (floatx4){0.f, 0.f, 0.f, 0.f};

    // staging: 4 rounds per operand; row = L>>7 (128 B/row), 8 chunks/row
    int srow[4], scg[4];
    #pragma unroll
    for (int it = 0; it < 4; it++) {
        int L = it * 4096 + w * 1024 + lane * 16;
        int rr = L >> 7;
        int cp = (L >> 4) & 7;
        srow[it] = rr;
        scg[it]  = cp ^ (rr & 7);
    }

    for (int k0 = 0; k0 < K; k0 += 64) {
        #pragma unroll
        for (int it = 0; it < 4; it++) {
            int ra = row0 + srow[it]; if (ra >= M) ra = M - 1;
            gl2lds16(A + (size_t)ra * K + k0 + scg[it] * 8,
                     As + (it * 4096 + w * 1024) / 2);
            int rb = col0 + srow[it];
            gl2lds16(Bt + (size_t)rb * K + k0 + scg[it] * 8,
                     Bs + (it * 4096 + w * 1024) / 2);
        }
        __syncthreads();

        #pragma unroll
        for (int j = 0; j < 2; j++) {
            bf16x8 fA[4], fB[4];
            #pragma unroll
            for (int mi = 0; mi < 4; mi++) {
                int rr = wm * 64 + mi * 16 + l16;
                __builtin_memcpy(&fA[mi],
                    &As[rr * 64 + (((j * 4 + quad) ^ (rr & 7)) * 8)], 16);
            }
            #pragma unroll
            for (int ni = 0; ni < 4; ni++) {
                int rr = wn * 64 + ni * 16 + l16;
                __builtin_memcpy(&fB[ni],
                    &Bs[rr * 64 + (((j * 4 + quad) ^ (rr & 7)) * 8)], 16);
            }
            #pragma unroll
            for (int mi = 0; mi < 4; mi++)
                #pragma unroll
                for (int ni = 0; ni < 4; ni++)
                    acc[mi][ni] = __builtin_amdgcn_mfma_f32_16x16x32_bf16(
                        fB[ni], fA[mi], acc[mi][ni], 0, 0, 0);
        }
        __syncthreads();
    }

    #pragma unroll
    for (int mi = 0; mi < 4; mi++) {
        int row = row0 + wm * 64 + mi * 16 + l16;
        if (row < M) {
            #pragma unroll
            for (int ni = 0; ni < 4; ni++) {
                floatx4 a = acc[mi][ni];
                unsigned int p0 = (unsigned int)f2b(a[0]) | ((unsigned int)f2b(a[1]) << 16);
                unsigned int p1 = (unsigned int)f2b(a[2]) | ((unsigned int)f2b(a[3]) << 16);
                *(uint2*)(C + (size_t)row * N + col0 + wn * 64 + ni * 16 + quad * 4) =
                    make_uint2(p0, p1);
            }
        }
    }
}

// ---------------------------------------------------------------------------
// Fused GAT (4 heads x 128, concat 512) + bias + BN + ReLU. In-place on H.
// (verified best: R7/R11, 1338 us)
// ---------------------------------------------------------------------------
__global__ __launch_bounds__(256)
void gat4_fused_kernel(unsigned short* __restrict__ H,     // [chunk*40, 512]
                       const int* __restrict__ edge,
                       const float* __restrict__ avs, const float* __restrict__ avd,
                       const float* __restrict__ bias,
                       const float* __restrict__ bng, const float* __restrict__ bnb,
                       const float* __restrict__ bnm, const float* __restrict__ bnv,
                       int g0)
{
    __shared__ __align__(16) unsigned short ht[D0 * NPG];   // 40960 B [512][40]
    __shared__ float es[4 * NPG], ed[4 * NPG];              // [head][node]
    __shared__ __align__(16) unsigned char cnt[NPG * 48];   // [dn][s]
    __shared__ short2 eloc[ESL];
    const int tid = threadIdx.x;
    const int lane = tid & 63, w = tid >> 6;                // wave = head
    const int quad = lane >> 4, l16 = lane & 15;
    const int gg = g0 + blockIdx.x;
    unsigned short* Hg = H + (size_t)blockIdx.x * NPG * D0;

    // ---- phase 0: init + edge load + transpose-stage ----
    for (int i = tid; i < NPG * 48 / 4; i += 256) ((unsigned int*)cnt)[i] = 0u;
    for (int i = tid; i < ESL; i += 256) {
        if (i < EPG) {
            int s  = edge[(size_t)gg * EPG + i] - gg * NPG;
            int dd = edge[(size_t)ETOT + (size_t)gg * EPG + i] - gg * NPG;
            eloc[i] = make_short2((short)s, (short)dd);
        } else {
            short v = (short)(i - EPG);
            eloc[i] = make_short2(v, v);
        }
    }
    for (int u = tid; u < 64 * (NPG / 4); u += 256) {       // 640 units
        int c8 = u & 63, gi = u >> 6;
        const unsigned short* src = Hg + (size_t)(4 * gi) * D0 + c8 * 8;
        uint4 v0 = *(const uint4*)(src);
        uint4 v1 = *(const uint4*)(src + D0);
        uint4 v2 = *(const uint4*)(src + 2 * D0);
        uint4 v3 = *(const uint4*)(src + 3 * D0);
        unsigned int a0[4] = {v0.x, v0.y, v0.z, v0.w};
        unsigned int a1[4] = {v1.x, v1.y, v1.z, v1.w};
        unsigned int a2[4] = {v2.x, v2.y, v2.z, v2.w};
        unsigned int a3[4] = {v3.x, v3.y, v3.z, v3.w};
        #pragma unroll
        for (int k = 0; k < 8; k++) {
            const int ws = k >> 1, sh = (k & 1) * 16;
            unsigned int w0 = ((a0[ws] >> sh) & 0xffffu) | (((a1[ws] >> sh) & 0xffffu) << 16);
            unsigned int w1 = ((a2[ws] >> sh) & 0xffffu) | (((a3[ws] >> sh) & 0xffffu) << 16);
            *(uint2*)&ht[htoff(c8 * 8 + k, 4 * gi)] = make_uint2(w0, w1);
        }
    }
    __syncthreads();

    // ---- phase 1: logits (wave w = head w) + edge-count build ----
    {
        float as0=0,as1=0,as2=0,as3=0, ad0=0,ad1=0,ad2=0,ad3=0;
        for (int ci = 0; ci < 32; ci++) {
            int c = quad + ci * 4;
            int chv = w * 128 + c;
            uint2 hv = *(const uint2*)&ht[htoff(chv, 4 * l16)];
            float h0 = lo16(hv.x), h1 = hi16(hv.x), h2 = lo16(hv.y), h3 = hi16(hv.y);
            float vs = avs[chv], vd = avd[chv];
            as0 += h0*vs; as1 += h1*vs; as2 += h2*vs; as3 += h3*vs;
            ad0 += h0*vd; ad1 += h1*vd; ad2 += h2*vd; ad3 += h3*vd;
        }
        #define RED4(x) x += __shfl_xor(x, 16); x += __shfl_xor(x, 32);
        RED4(as0) RED4(as1) RED4(as2) RED4(as3)
        RED4(ad0) RED4(ad1) RED4(ad2) RED4(ad3)
        #undef RED4
        if (quad == 0) {
            float rs[4] = {as0, as1, as2, as3};
            float rd[4] = {ad0, ad1, ad2, ad3};
            #pragma unroll
            for (int rr = 0; rr < 4; rr++) {
                int node = 4 * l16 + rr;
                if (node < NPG) { es[w * NPG + node] = rs[rr]; ed[w * NPG + node] = rd[rr]; }
            }
        }
    }
    for (int e = tid; e < ESL; e += 256) {
        short2 sd = eloc[e];
        atomicAdd((unsigned int*)cnt + ((sd.y * 48 + sd.x) >> 2),
                  1u << ((sd.x & 3) * 8));
    }
    __syncthreads();

    // ---- phase 2: in-register alpha (masked max + den via shfl) + MFMA ----
    {
        bf16x8 ahi[3][2], alo[3][2];
        float esv0[8], esv1[8];
        #pragma unroll
        for (int j = 0; j < 8; j++) {
            esv0[j] = es[w * NPG + quad * 8 + j];
            esv1[j] = (quad == 0) ? es[w * NPG + 32 + j] : 0.f;
        }
        #pragma unroll
        for (int mt = 0; mt < 3; mt++) {
            int dn = mt * 16 + l16;
            bool ok = dn < NPG;
            float edv = 0.f;
            uint2 c0 = make_uint2(0u, 0u), c1 = make_uint2(0u, 0u);
            if (ok) {
                edv = ed[w * NPG + dn];
                c0 = *(const uint2*)&cnt[dn * 48 + quad * 8];
                if (quad == 0) c1 = *(const uint2*)&cnt[dn * 48 + 32];
            }
            float v0[8], v1[8];
            int cb0[8], cb1[8];
            float pm = -1e30f;
            #pragma unroll
            for (int j = 0; j < 8; j++) {
                cb0[j] = (int)(((j < 4 ? c0.x : c0.y) >> ((j & 3) * 8)) & 0xffu);
                float t0 = esv0[j] + edv;
                v0[j] = t0 > 0.f ? t0 : 0.2f * t0;
                if (cb0[j]) pm = fmaxf(pm, v0[j]);
                cb1[j] = (int)(((j < 4 ? c1.x : c1.y) >> ((j & 3) * 8)) & 0xffu);
                float t1 = esv1[j] + edv;
                v1[j] = t1 > 0.f ? t1 : 0.2f * t1;
                if (cb1[j]) pm = fmaxf(pm, v1[j]);
            }
            pm = fmaxf(pm, __shfl_xor(pm, 16));
            pm = fmaxf(pm, __shfl_xor(pm, 32));
            float e0[8], e1[8], pd = 0.f;
            #pragma unroll
            for (int j = 0; j < 8; j++) {
                e0[j] = cb0[j] ? (float)cb0[j] * __expf(v0[j] - pm) : 0.f;
                e1[j] = cb1[j] ? (float)cb1[j] * __expf(v1[j] - pm) : 0.f;
                pd += e0[j] + e1[j];
            }
            pd += __shfl_xor(pd, 16);
            pd += __shfl_xor(pd, 32);
            float di = ok ? 1.f / pd : 0.f;
            #pragma unroll
            for (int j = 0; j < 8; j++) {
                float a0 = e0[j] * di;
                unsigned short hb0 = f2b(a0);
                ahi[mt][0][j] = (short)hb0;
                alo[mt][0][j] = (short)f2b(a0 - b2f(hb0));
                float a1 = e1[j] * di;
                unsigned short hb1 = f2b(a1);
                ahi[mt][1][j] = (short)hb1;
                alo[mt][1][j] = (short)f2b(a1 - b2f(hb1));
            }
        }
        const floatx4 z = {0.f, 0.f, 0.f, 0.f};
        for (int nt = 0; nt < 8; nt++) {
            const int ch0 = w * 128 + nt * 16;
            bf16x8 b0, b1 = {0,0,0,0,0,0,0,0};
            __builtin_memcpy(&b0, &ht[htoff(ch0 + l16, quad * 8)], 16);
            if (quad == 0) __builtin_memcpy(&b1, &ht[htoff(ch0 + l16, 32)], 16);
            floatx4 acc0 = z, acc1 = z, acc2 = z;
            acc0 = __builtin_amdgcn_mfma_f32_16x16x32_bf16(ahi[0][0], b0, acc0, 0, 0, 0);
            acc1 = __builtin_amdgcn_mfma_f32_16x16x32_bf16(ahi[1][0], b0, acc1, 0, 0, 0);
            acc2 = __builtin_amdgcn_mfma_f32_16x16x32_bf16(ahi[2][0], b0, acc2, 0, 0, 0);
            acc0 = __builtin_amdgcn_mfma_f32_16x16x32_bf16(alo[0][0], b0, acc0, 0, 0, 0);
            acc1 = __builtin_amdgcn_mfma_f32_16x16x32_bf16(alo[1][0], b0, acc1, 0, 0, 0);
            acc2 = __builtin_amdgcn_mfma_f32_16x16x32_bf16(alo[2][0], b0, acc2, 0, 0, 0);
            acc0 = __builtin_amdgcn_mfma_f32_16x16x32_bf16(ahi[0][1], b1, acc0, 0, 0, 0);
            acc1 = __builtin_amdgcn_mfma_f32_16x16x32_bf16(ahi[1][1], b1, acc1, 0, 0, 0);
            acc2 = __builtin_amdgcn_mfma_f32_16x16x32_bf16(ahi[2][1], b1, acc2, 0, 0, 0);
            acc0 = __builtin_amdgcn_mfma_f32_16x16x32_bf16(alo[0][1], b1, acc0, 0, 0, 0);
            acc1 = __builtin_amdgcn_mfma_f32_16x16x32_bf16(alo[1][1], b1, acc1, 0, 0, 0);
            acc2 = __builtin_amdgcn_mfma_f32_16x16x32_bf16(alo[2][1], b1, acc2, 0, 0, 0);
            const int c = ch0 + l16;
            float scl = rsqrtf(bnv[c] + BN_EPS) * bng[c];
            float sft = (bias[c] - bnm[c]) * scl + bnb[c];
            unsigned short* reg = &ht[ch0 * 40];
            #pragma unroll
            for (int mt = 0; mt < 3; mt++) {
                floatx4 a = (mt == 0) ? acc0 : (mt == 1) ? acc1 : acc2;
                #pragma unroll
                for (int rr = 0; rr < 4; rr++) {
                    int dn = mt * 16 + quad * 4 + rr;
                    if (dn < NPG) {
                        float o = a[rr] * scl + sft;
                        o = fmaxf(o, 0.f);
                        reg[dn * 16 + l16] = f2b(o);
                    }
                }
            }
        }
    }
    __syncthreads();
    // ---- coalesced writeback ----
    for (int u = tid; u < NPG * 64; u += 256) {
        int s = u >> 6, c8 = u & 63;
        const unsigned short* reg = &ht[(c8 >> 1) * 16 * 40];
        uint4 v = *(const uint4*)&reg[s * 16 + (c8 & 1) * 8];
        *(uint4*)(Hg + (size_t)s * D0 + c8 * 8) = v;
    }
}

// ---------------------------------------------------------------------------
// Fused GAT (1 head, 128) + bias + BN (no relu) + mean/max pool -> cmb.
// (verified R7/R11)
// ---------------------------------------------------------------------------
__global__ __launch_bounds__(256)
void gat1_pool_fused_kernel(const unsigned short* __restrict__ H,  // [chunk*40,128]
                            const int* __restrict__ edge,
                            const float* __restrict__ avs, const float* __restrict__ avd,
                            const float* __restrict__ bias,
                            const float* __restrict__ bng, const float* __restrict__ bnb,
                            const float* __restrict__ bnm, const float* __restrict__ bnv,
                            float* __restrict__ cmb, int colbase, int g0)
{
    __shared__ __align__(16) unsigned short ht[HID * NPG];  // 10240 B
    __shared__ float es[NPG], ed[NPG];
    __shared__ __align__(16) unsigned char cnt[NPG * 48];
    __shared__ short2 eloc[ESL];
    const int tid = threadIdx.x;
    const int lane = tid & 63, w = tid >> 6;
    const int quad = lane >> 4, l16 = lane & 15;
    const int gg = g0 + blockIdx.x;
    const unsigned short* Hg = H + (size_t)blockIdx.x * NPG * HID;

    for (int i = tid; i < NPG * 48 / 4; i += 256) ((unsigned int*)cnt)[i] = 0u;
    for (int i = tid; i < ESL; i += 256) {
        if (i < EPG) {
            int s  = edge[(size_t)gg * EPG + i] - gg * NPG;
            int dd = edge[(size_t)ETOT + (size_t)gg * EPG + i] - gg * NPG;
            eloc[i] = make_short2((short)s, (short)dd);
        } else {
            short v = (short)(i - EPG);
            eloc[i] = make_short2(v, v);
        }
    }
    for (int u = tid; u < 16 * (NPG / 4); u += 256) {       // 160 units
        int c8 = u & 15, gi = u >> 4;
        const unsigned short* src = Hg + (size_t)(4 * gi) * HID + c8 * 8;
        uint4 v0 = *(const uint4*)(src);
        uint4 v1 = *(const uint4*)(src + HID);
        uint4 v2 = *(const uint4*)(src + 2 * HID);
        uint4 v3 = *(const uint4*)(src + 3 * HID);
        unsigned int a0[4] = {v0.x, v0.y, v0.z, v0.w};
        unsigned int a1[4] = {v1.x, v1.y, v1.z, v1.w};
        unsigned int a2[4] = {v2.x, v2.y, v2.z, v2.w};
        unsigned int a3[4] = {v3.x, v3.y, v3.z, v3.w};
        #pragma unroll
        for (int k = 0; k < 8; k++) {
            const int ws = k >> 1, sh = (k & 1) * 16;
            unsigned int w0 = ((a0[ws] >> sh) & 0xffffu) | (((a1[ws] >> sh) & 0xffffu) << 16);
            unsigned int w1 = ((a2[ws] >> sh) & 0xffffu) | (((a3[ws] >> sh) & 0xffffu) << 16);
            *(uint2*)&ht[htoff(c8 * 8 + k, 4 * gi)] = make_uint2(w0, w1);
        }
    }
    __syncthreads();

    // logits: wave0 -> es, wave1 -> ed; cnt build (all threads)
    if (w < 2) {
        const float* av = w ? avd : avs;
        float a0=0,a1=0,a2=0,a3=0;
        for (int ci = 0; ci < 32; ci++) {
            int c = quad + ci * 4;
            uint2 hv = *(const uint2*)&ht[htoff(c, 4 * l16)];
            float vc = av[c];
            a0 += lo16(hv.x)*vc; a1 += hi16(hv.x)*vc;
            a2 += lo16(hv.y)*vc; a3 += hi16(hv.y)*vc;
        }
        #define RED4(x) x += __shfl_xor(x, 16); x += __shfl_xor(x, 32);
        RED4(a0) RED4(a1) RED4(a2) RED4(a3)
        #undef RED4
        if (quad == 0) {
            float rv[4] = {a0, a1, a2, a3};
            float* dst = w ? ed : es;
            #pragma unroll
            for (int rr = 0; rr < 4; rr++) {
                int node = 4 * l16 + rr;
                if (node < NPG) dst[node] = rv[rr];
            }
        }
    }
    for (int e = tid; e < ESL; e += 256) {
        short2 sd = eloc[e];
        atomicAdd((unsigned int*)cnt + ((sd.y * 48 + sd.x) >> 2),
                  1u << ((sd.x & 3) * 8));
    }
    __syncthreads();

    // ---- in-register alpha + MFMA + pool ----
    {
        bf16x8 ahi[3][2], alo[3][2];
        float esv0[8], esv1[8];
        #pragma unroll
        for (int j = 0; j < 8; j++) {
            esv0[j] = es[quad * 8 + j];
            esv1[j] = (quad == 0) ? es[32 + j] : 0.f;
        }
        #pragma unroll
        for (int mt = 0; mt < 3; mt++) {
            int dn = mt * 16 + l16;
            bool ok = dn < NPG;
            float edv = 0.f;
            uint2 c0 = make_uint2(0u, 0u), c1 = make_uint2(0u, 0u);
            if (ok) {
                edv = ed[dn];
                c0 = *(const uint2*)&cnt[dn * 48 + quad * 8];
                if (quad == 0) c1 = *(const uint2*)&cnt[dn * 48 + 32];
            }
            float v0[8], v1[8];
            int cb0[8], cb1[8];
            float pm = -1e30f;
            #pragma unroll
            for (int j = 0; j < 8; j++) {
                cb0[j] = (int)(((j < 4 ? c0.x : c0.y) >> ((j & 3) * 8)) & 0xffu);
                float t0 = esv0[j] + edv;
                v0[j] = t0 > 0.f ? t0 : 0.2f * t0;
                if (cb0[j]) pm = fmaxf(pm, v0[j]);
                cb1[j] = (int)(((j < 4 ? c1.x : c1.y) >> ((j & 3) * 8)) & 0xffu);
                float t1 = esv1[j] + edv;
                v1[j] = t1 > 0.f ? t1 : 0.2f * t1;
                if (cb1[j]) pm = fmaxf(pm, v1[j]);
            }
            pm = fmaxf(pm, __shfl_xor(pm, 16));
            pm = fmaxf(pm, __shfl_xor(pm, 32));
            float e0[8], e1[8], pd = 0.f;
            #pragma unroll
            for (int j = 0; j < 8; j++) {
                e0[j] = cb0[j] ? (float)cb0[j] * __expf(v0[j] - pm) : 0.f;
                e1[j] = cb1[j] ? (float)cb1[j] * __expf(v1[j] - pm) : 0.f;
                pd += e0[j] + e1[j];
            }
            pd += __shfl_xor(pd, 16);
            pd += __shfl_xor(pd, 32);
            float di = ok ? 1.f / pd : 0.f;
            #pragma unroll
            for (int j = 0; j < 8; j++) {
                float a0 = e0[j] * di;
                unsigned short hb0 = f2b(a0);
                ahi[mt][0][j] = (short)hb0;
                alo[mt][0][j] = (short)f2b(a0 - b2f(hb0));
                float a1 = e1[j] * di;
                unsigned short hb1 = f2b(a1);
                ahi[mt][1][j] = (short)hb1;
                alo[mt][1][j] = (short)f2b(a1 - b2f(hb1));
            }
        }
        const floatx4 z = {0.f, 0.f, 0.f, 0.f};
        for (int t2 = 0; t2 < 2; t2++) {
            const int ch0 = (w * 2 + t2) * 16;
            bf16x8 b0, b1 = {0,0,0,0,0,0,0,0};
            __builtin_memcpy(&b0, &ht[htoff(ch0 + l16, quad * 8)], 16);
            if (quad == 0) __builtin_memcpy(&b1, &ht[htoff(ch0 + l16, 32)], 16);
            floatx4 acc0 = z, acc1 = z, acc2 = z;
            acc0 = __builtin_amdgcn_mfma_f32_16x16x32_bf16(ahi[0][0], b0, acc0, 0, 0, 0);
            acc1 = __builtin_amdgcn_mfma_f32_16x16x32_bf16(ahi[1][0], b0, acc1, 0, 0, 0);
            acc2 = __builtin_amdgcn_mfma_f32_16x16x32_bf16(ahi[2][0], b0, acc2, 0, 0, 0);
            acc0 = __builtin_amdgcn_mfma_f32_16x16x32_bf16(alo[0][0], b0, acc0, 0, 0, 0);
            acc1 = __builtin_amdgcn_mfma_f32_16x16x32_bf16(alo[1][0], b0, acc1, 0, 0, 0);
            acc2 = __builtin_amdgcn_mfma_f32_16x16x32_bf16(alo[2][0], b0, acc2, 0, 0, 0);
            acc0 = __builtin_amdgcn_mfma_f32_16x16x32_bf16(ahi[0][1], b1, acc0, 0, 0, 0);
            acc1 = __builtin_amdgcn_mfma_f32_16x16x32_bf16(ahi[1][1], b1, acc1, 0, 0, 0);
            acc2 = __builtin_amdgcn_mfma_f32_16x16x32_bf16(ahi[2][1], b1, acc2, 0, 0, 0);
            acc0 = __builtin_amdgcn_mfma_f32_16x16x32_bf16(alo[0][1], b1, acc0, 0, 0, 0);
            acc1 = __builtin_amdgcn_mfma_f32_16x16x32_bf16(alo[1][1], b1, acc1, 0, 0, 0);
            acc2 = __builtin_amdgcn_mfma_f32_16x16x32_bf16(alo[2][1], b1, acc2, 0, 0, 0);
            const int c = ch0 + l16;
            float scl = rsqrtf(bnv[c] + BN_EPS) * bng[c];
            float sft = (bias[c] - bnm[c]) * scl + bnb[c];
            float psum = 0.f, pmax = -1e30f;
            #pragma unroll
            for (int mt = 0; mt < 3; mt++) {
                floatx4 a = (mt == 0) ? acc0 : (mt == 1) ? acc1 : acc2;
                #pragma unroll
                for (int rr = 0; rr < 4; rr++) {
                    int dn = mt * 16 + quad * 4 + rr;
                    if (dn < NPG) {
                        float o = a[rr] * scl + sft;   // no relu
                        psum += o;
                        pmax = fmaxf(pmax, o);
                    }
                }
            }
            psum += __shfl_xor(psum, 16); psum += __shfl_xor(psum, 32);
            pmax = fmaxf(pmax, __shfl_xor(pmax, 16));
            pmax = fmaxf(pmax, __shfl_xor(pmax, 32));
            if (quad == 0) {
                cmb[(size_t)gg * 512 + colbase + c] = psum * (1.f / NPG);
                cmb[(size_t)gg * 512 + colbase + HID + c] = pmax;
            }
        }
    }
}

// ---------------------------------------------------------------------------
// Fused MFMA MLP (verified round 4): 16 graphs/block, 256 blocks.
// ---------------------------------------------------------------------------
__global__ __launch_bounds__(256)
void mlp_mfma_kernel(const float* __restrict__ cmb, const float* __restrict__ addf,
                     const unsigned short* __restrict__ W0hi, const unsigned short* __restrict__ W0lo,
                     const float* __restrict__ b0, const float* __restrict__ g0v,
                     const float* __restrict__ be0, const float* __restrict__ m0,
                     const float* __restrict__ v0,
                     const unsigned short* __restrict__ W1hi, const unsigned short* __restrict__ W1lo,
                     const float* __restrict__ b1, const float* __restrict__ g1v,
                     const float* __restrict__ be1, const float* __restrict__ m1,
                     const float* __restrict__ v1,
                     const float* __restrict__ W2, const float* __restrict__ b2,
                     float* __restrict__ out)
{
    __shared__ __align__(16) unsigned short a0hi[16 * A0ST], a0lo[16 * A0ST];
    __shared__ __align__(16) unsigned short h1hi[16 * H1ST], h1lo[16 * H1ST];
    __shared__ float h2[16 * H2ST];
    const int tid = threadIdx.x;
    const int lane = tid & 63, w = tid >> 6;
    const int quad = lane >> 4, l16 = lane & 15;
    const int gb = blockIdx.x * 16;

    for (int i = tid; i < 16 * KPM; i += 256) {
        int g = i / KPM, k = i - g * KPM;
        float x = 0.f;
        if (k < 512) x = cmb[(size_t)(gb + g) * 512 + k];
        else if (k < CMB) x = addf[(gb + g) * 8 + (k - 512)];
        unsigned short hb = f2b(x);
        a0hi[g * A0ST + k] = hb;
        a0lo[g * A0ST + k] = f2b(x - b2f(hb));
    }
    __syncthreads();

    {
        floatx4 acc[4];
        #pragma unroll
        for (int ni = 0; ni < 4; ni++) acc[ni] = (floatx4){0.f, 0.f, 0.f, 0.f};
        for (int k0 = 0; k0 < KPM; k0 += 32) {
            bf16x8 fah, fal;
            __builtin_memcpy(&fah, &a0hi[l16 * A0ST + k0 + quad * 8], 16);
            __builtin_memcpy(&fal, &a0lo[l16 * A0ST + k0 + quad * 8], 16);
            #pragma unroll
            for (int ni = 0; ni < 4; ni++) {
                int row = w * 64 + ni * 16 + l16;
                bf16x8 fwh, fwl;
                __builtin_memcpy(&fwh, &W0hi[(size_t)row * KPM + k0 + quad * 8], 16);
                __builtin_memcpy(&fwl, &W0lo[(size_t)row * KPM + k0 + quad * 8], 16);
                acc[ni] = __builtin_amdgcn_mfma_f32_16x16x32_bf16(fwh, fah, acc[ni], 0, 0, 0);
                acc[ni] = __builtin_amdgcn_mfma_f32_16x16x32_bf16(fwh, fal, acc[ni], 0, 0, 0);
                acc[ni] = __builtin_amdgcn_mfma_f32_16x16x32_bf16(fwl, fah, acc[ni], 0, 0, 0);
            }
        }
        #pragma unroll
        for (int ni = 0; ni < 4; ni++) {
            int cbase = w * 64 + ni * 16 + quad * 4;
            unsigned int ph[2], pl[2];
            #pragma unroll
            for (int j = 0; j < 2; j++) {
                unsigned int hh[2], ll[2];
                #pragma unroll
                for (int q = 0; q < 2; q++) {
                    int rr = 2 * j + q, c = cbase + rr;
                    float scl = rsqrtf(v0[c] + BN_EPS) * g0v[c];
                    float val = (acc[ni][rr] + b0[c] - m0[c]) * scl + be0[c];
                    val = fmaxf(val, 0.f);
                    unsigned short hb = f2b(val);
                    hh[q] = hb;
                    ll[q] = f2b(val - b2f(hb));
                }
                ph[j] = hh[0] | (hh[1] << 16);
                pl[j] = ll[0] | (ll[1] << 16);
            }
            *(uint2*)&h1hi[l16 * H1ST + cbase] = make_uint2(ph[0], ph[1]);
            *(uint2*)&h1lo[l16 * H1ST + cbase] = make_uint2(pl[0], pl[1]);
        }
    }
    __syncthreads();

    {
        floatx4 acc[2];
        acc[0] = (floatx4){0.f, 0.f, 0.f, 0.f};
        acc[1] = (floatx4){0.f, 0.f, 0.f, 0.f};
        for (int k0 = 0; k0 < 256; k0 += 32) {
            bf16x8 fah, fal;
            __builtin_memcpy(&fah, &h1hi[l16 * H1ST + k0 + quad * 8], 16);
            __builtin_memcpy(&fal, &h1lo[l16 * H1ST + k0 + quad * 8], 16);
            #pragma unroll
            for (int ni = 0; ni < 2; ni++) {
                int row = w * 32 + ni * 16 + l16;
                bf16x8 fwh, fwl;
                __builtin_memcpy(&fwh, &W1hi[(size_t)row * 256 + k0 + quad * 8], 16);
                __builtin_memcpy(&fwl, &W1lo[(size_t)row * 256 + k0 + quad * 8], 16);
                acc[ni] = __builtin_amdgcn_mfma_f32_16x16x32_bf16(fwh, fah, acc[ni], 0, 0, 0);
                acc[ni] = __builtin_amdgcn_mfma_f32_16x16x32_bf16(fwh, fal, acc[ni], 0, 0, 0);
                acc[ni] = __builtin_amdgcn_mfma_f32_16x16x32_bf16(fwl, fah, acc[ni], 0, 0, 0);
            }
        }
        #pragma unroll
        for (int ni = 0; ni < 2; ni++) {
            #pragma unroll
            for (int rr = 0; rr < 4; rr++) {
                int c = w * 32 + ni * 16 + quad * 4 + rr;
                float scl = rsqrtf(v1[c] + BN_EPS) * g1v[c];
                float val = (acc[ni][rr] + b1[c] - m1[c]) * scl + be1[c];
                h2[l16 * H2ST + c] = fmaxf(val, 0.f);
            }
        }
    }
    __syncthreads();

    {
        int g = tid >> 4, part = tid & 15;
        float s = 0.f;
        #pragma unroll
        for (int j = 0; j < 8; j++)
            s += h2[g * H2ST + part * 8 + j] * W2[part * 8 + j];
        s += __shfl_xor(s, 1); s += __shfl_xor(s, 2);
        s += __shfl_xor(s, 4); s += __shfl_xor(s, 8);
        if (part == 0) out[gb + g] = 1.f / (1.f + __expf(-(s + b2[0])));
    }
}

// ---------------------------------------------------------------------------
extern "C" void kernel_launch(void* const* d_in, const int* in_sizes, int n_in,
                              void* d_out, int out_size, void* d_ws, size_t ws_size,
                              hipStream_t stream)
{
    float* out = (float*)d_out;
    int out_n = out_size < 4096 ? out_size : 4096;

    const float* x_a  = (const float*)d_in[0];
    const int*   edge_a = (const int*)d_in[1];
    const float* x_b  = (const float*)d_in[3];
    const int*   edge_b = (const int*)d_in[4];
    const float* addf = (const float*)d_in[6];
    const float* gW0 = (const float*)d_in[7],  *gb0 = (const float*)d_in[8];
    const float* gas0 = (const float*)d_in[9], *gad0 = (const float*)d_in[10];
    const float* gW1 = (const float*)d_in[11], *gb1 = (const float*)d_in[12];
    const float* gas1 = (const float*)d_in[13], *gad1 = (const float*)d_in[14];
    const float* gW2 = (const float*)d_in[15], *gb2 = (const float*)d_in[16];
    const float* gas2 = (const float*)d_in[17], *gad2 = (const float*)d_in[18];
    const float* bn0g = (const float*)d_in[19], *bn0b = (const float*)d_in[20];
    const float* bn0m = (const float*)d_in[21], *bn0v = (const float*)d_in[22];
    const float* bn1g = (const float*)d_in[23], *bn1b = (const float*)d_in[24];
    const float* bn1m = (const float*)d_in[25], *bn1v = (const float*)d_in[26];
    const float* bn2g = (const float*)d_in[27], *bn2b = (const float*)d_in[28];
    const float* bn2m = (const float*)d_in[29], *bn2v = (const float*)d_in[30];
    const float* mW0 = (const float*)d_in[31], *mb0 = (const float*)d_in[32];
    const float* mg0 = (const float*)d_in[33], *mbe0 = (const float*)d_in[34];
    const float* mm0 = (const float*)d_in[35], *mv0 = (const float*)d_in[36];
    const float* mW1 = (const float*)d_in[37], *mb1 = (const float*)d_in[38];
    const float* mg1 = (const float*)d_in[39], *mbe1 = (const float*)d_in[40];
    const float* mm1 = (const float*)d_in[41], *mv1 = (const float*)d_in[42];
    const float* mW2 = (const float*)d_in[43], *mb2 = (const float*)d_in[44];

    // ---- workspace layout ----
    char* p = (char*)d_ws;
    const size_t CMB_BYTES = (size_t)B_GRAPHS * 512 * sizeof(float);   // 8 MB
    float* cmb = (float*)p; p += CMB_BYTES;
    unsigned short* W0t = (unsigned short*)p; p += (size_t)D0 * KP0 * 2;
    unsigned short* W1t = (unsigned short*)p; p += (size_t)D0 * D0 * 2;
    unsigned short* W2t = (unsigned short*)p; p += (size_t)HID * D0 * 2;
    unsigned short* M0hi = (unsigned short*)p; p += (size_t)256 * KPM * 2;
    unsigned short* M0lo = (unsigned short*)p; p += (size_t)256 * KPM * 2;
    unsigned short* M1hi = (unsigned short*)p; p += (size_t)128 * 256 * 2;
    unsigned short* M1lo = (unsigned short*)p; p += (size_t)128 * 256 * 2;
    size_t used = (size_t)(p - (char*)d_ws);
    const size_t PG = 7680ull + 40960ull + 40960ull;   // Xb + B1 + B2
    int chunk = B_GRAPHS;
    while (chunk > 4 && used + (size_t)chunk * PG > ws_size) chunk >>= 1;
    if (used + (size_t)chunk * PG > ws_size) {
        write_code_kernel<<<(out_n + 255) / 256, 256, 0, stream>>>(out, out_n, 500000.f);
        return;
    }
    unsigned short* Xb = (unsigned short*)p; p += (size_t)chunk * 7680;
    unsigned short* B1 = (unsigned short*)p; p += (size_t)chunk * 40960;
    unsigned short* B2 = (unsigned short*)p;

    // ---- weight conversion (once) ----
    convw_kernel<<<(D0 * KP0 + 255) / 256, 256, 0, stream>>>(gW0, W0t, F_IN, D0, KP0);
    convw_kernel<<<(D0 * D0 + 255) / 256, 256, 0, stream>>>(gW1, W1t, D0, D0, D0);
    convw_kernel<<<(HID * D0 + 255) / 256, 256, 0, stream>>>(gW2, W2t, D0, HID, D0);
    convw_hilo_kernel<<<(256 * KPM + 255) / 256, 256, 0, stream>>>(
        mW0, M0hi, M0lo, CMB, 256, KPM);
    convw_hilo_kernel<<<(128 * 256 + 255) / 256, 256, 0, stream>>>(
        mW1, M1hi, M1lo, 256, 128, 256);

    for (int drug = 0; drug < 2; drug++) {
        const float* x = drug ? x_b : x_a;
        const int* edge = drug ? edge_b : edge_a;
        int colbase = drug ? 256 : 0;

        for (int g0 = 0; g0 < B_GRAPHS; g0 += chunk) {
            int n = chunk * NPG;
            int gy = (n + 127) / 128;
            // layer 0 (K=96 -> BK=32 kernel)
            convx_kernel<<<(n * (KP0 / 8) + 255) / 256, 256, 0, stream>>>(
                x + (size_t)g0 * NPG * F_IN, Xb, n);
            gemm_mfma_kernel<<<dim3(D0 / 128, gy), 256, 0, stream>>>(
                Xb, W0t, B1, n, KP0, D0);
            gat4_fused_kernel<<<chunk, 256, 0, stream>>>(
                B1, edge, gas0, gad0, gb0, bn0g, bn0b, bn0m, bn0v, g0);
            // layer 1 (K=512 -> BK=64 kernel)
            gemm_mfma64_kernel<<<dim3(D0 / 128, gy), 256, 0, stream>>>(
                B1, W1t, B2, n, D0, D0);
            gat4_fused_kernel<<<chunk, 256, 0, stream>>>(
                B2, edge, gas1, gad1, gb1, bn1g, bn1b, bn1m, bn1v, g0);
            // layer 2 (K=512 -> BK=64 kernel)
            gemm_mfma64_kernel<<<dim3(HID / 128, gy), 256, 0, stream>>>(
                B2, W2t, B1, n, D0, HID);
            gat1_pool_fused_kernel<<<chunk, 256, 0, stream>>>(
                B1, edge, gas2, gad2, gb2, bn2g, bn2b, bn2m, bn2v,
                cmb, colbase, g0);
        }
    }
    mlp_mfma_kernel<<<B_GRAPHS / 16, 256, 0, stream>>>(
        cmb, addf, M0hi, M0lo, mb0, mg0, mbe0, mm0, mv0,
        M1hi, M1lo, mb1, mg1, mbe1, mm1, mv1, mW2, mb2, out);
}